// Round 1
// baseline (818.487 us; speedup 1.0000x reference)
//
#include <hip/hip_runtime.h>

typedef unsigned short u16;
typedef short s16x8 __attribute__((ext_vector_type(8)));
typedef u16 u16x8 __attribute__((ext_vector_type(8)));
typedef u16 u16x4 __attribute__((ext_vector_type(4)));
typedef float f32x4 __attribute__((ext_vector_type(4)));

#define MFMA16(A, B, C) __builtin_amdgcn_mfma_f32_16x16x32_bf16(A, B, C, 0, 0, 0)

__device__ __forceinline__ u16 f2b(float f) {
  union { float f; unsigned u; } v; v.f = f;
  unsigned r = v.u + 0x7fffu + ((v.u >> 16) & 1u);
  return (u16)(r >> 16);
}
__device__ __forceinline__ float b2f(u16 u) {
  union { unsigned u; float f; } v; v.u = ((unsigned)u) << 16;
  return v.f;
}

// ---------------- fp32 -> bf16 convert (vectorized) ----------------
__global__ __launch_bounds__(256) void cvt_f32_bf16(const float* __restrict__ src,
                                                    u16* __restrict__ dst, int n4) {
  int i = blockIdx.x * 256 + threadIdx.x;
  if (i >= n4) return;
  float4 v = ((const float4*)src)[i];
  u16x4 o;
  o[0] = f2b(v.x); o[1] = f2b(v.y); o[2] = f2b(v.z); o[3] = f2b(v.w);
  ((u16x4*)dst)[i] = o;
}

// ---------------- RoPE cos/sin table: [2048][64] float2 ----------------
__global__ __launch_bounds__(256) void rope_table_k(float2* __restrict__ tbl) {
  int t = blockIdx.x * 256 + threadIdx.x;  // 131072 total
  int l = t >> 6, d = t & 63;
  float freq = exp2f(-0.20762050593045952f * (float)d);  // 10000^(-d/64)
  float a = (float)l * freq;
  float s, c;
  sincosf(a, &s, &c);
  tbl[t] = make_float2(c, s);
}

// ---------------- RoPE apply in-place on Q and K ([B,L,D] bf16) ----------------
__global__ __launch_bounds__(256) void rope_apply_k(u16* __restrict__ Q, u16* __restrict__ K,
                                                    const float2* __restrict__ tbl,
                                                    float qscale) {
  int t = blockIdx.x * 256 + threadIdx.x;  // 1,048,576 total
  int tensor = t >> 19;
  int idx = t & 524287;
  int g = idx & 7;           // d-group: d0 = g*8 in [0,64)
  int rest = idx >> 3;       // b*32768 + l*16 + h
  int h = rest & 15;
  int l = (rest >> 4) & 2047;
  int b = rest >> 15;
  u16* base = (tensor ? K : Q) + (((size_t)(b * 2048 + l)) << 11) + h * 128 + g * 8;
  float sc = tensor ? 1.0f : qscale;
  u16x8 v1 = *(const u16x8*)base;        // d..d+8
  u16x8 v2 = *(const u16x8*)(base + 64); // d+64..d+72
  const float2* cs = tbl + l * 64 + g * 8;
  u16x8 o1, o2;
#pragma unroll
  for (int j = 0; j < 8; ++j) {
    float a = b2f((u16)v1[j]), bb = b2f((u16)v2[j]);
    float c = cs[j].x, s = cs[j].y;
    o1[j] = f2b((a * c - bb * s) * sc);
    o2[j] = f2b((bb * c + a * s) * sc);
  }
  *(u16x8*)base = o1;
  *(u16x8*)(base + 64) = o2;
}

// ---------------- bf16 NT GEMM: C[m,n] = sum_k A[m,k]*B[n,k] ----------------
// MODE 0: fp32 row-major out; MODE 1: bf16 row-major out; MODE 2: bf16 V^T out
// (Vt[b,h,d,l]: idx = (m>>11)<<22 | n<<11 | (m&2047), valid for M=4096,N=2048,L=2048)
template <int MODE>
__global__ __launch_bounds__(256, 2) void gemm_nt(const u16* __restrict__ A,
                                                  const u16* __restrict__ B,
                                                  float* __restrict__ Cf,
                                                  u16* __restrict__ Cb,
                                                  int M, int N, int K) {
  __shared__ u16 sA[128 * 64];
  __shared__ u16 sB[128 * 64];
  const int tid = threadIdx.x;
  const int lane = tid & 63;
  const int w = tid >> 6;
  const int wr = (w >> 1) * 64;
  const int wc = (w & 1) * 64;
  const int qr = lane & 15;
  const int kg = lane >> 4;
  const size_t m0 = (size_t)blockIdx.y * 128;
  const size_t n0 = (size_t)blockIdx.x * 128;

  f32x4 acc[4][4] = {};

  for (int k0 = 0; k0 < K; k0 += 64) {
#pragma unroll
    for (int j = 0; j < 4; ++j) {
      int i = j * 256 + tid;
      const u16* ga = A + (m0 + (i >> 3)) * (size_t)K + k0 + (i & 7) * 8;
      __builtin_amdgcn_global_load_lds((const __attribute__((address_space(1))) void*)ga,
                                       (__attribute__((address_space(3))) void*)(sA + i * 8),
                                       16, 0, 0);
    }
#pragma unroll
    for (int j = 0; j < 4; ++j) {
      int i = j * 256 + tid;
      const u16* gb = B + (n0 + (i >> 3)) * (size_t)K + k0 + (i & 7) * 8;
      __builtin_amdgcn_global_load_lds((const __attribute__((address_space(1))) void*)gb,
                                       (__attribute__((address_space(3))) void*)(sB + i * 8),
                                       16, 0, 0);
    }
    __syncthreads();  // drains vmcnt(0) before LDS reads
#pragma unroll
    for (int kk = 0; kk < 2; ++kk) {
      const int ko = kk * 32 + kg * 8;
      s16x8 af[4], bfr[4];
#pragma unroll
      for (int mi = 0; mi < 4; ++mi)
        af[mi] = *(const s16x8*)(sA + (wr + mi * 16 + qr) * 64 + ko);
#pragma unroll
      for (int ni = 0; ni < 4; ++ni)
        bfr[ni] = *(const s16x8*)(sB + (wc + ni * 16 + qr) * 64 + ko);
#pragma unroll
      for (int mi = 0; mi < 4; ++mi)
#pragma unroll
        for (int ni = 0; ni < 4; ++ni)
          acc[mi][ni] = MFMA16(af[mi], bfr[ni], acc[mi][ni]);
    }
    __syncthreads();
  }

#pragma unroll
  for (int mi = 0; mi < 4; ++mi) {
#pragma unroll
    for (int ni = 0; ni < 4; ++ni) {
#pragma unroll
      for (int r = 0; r < 4; ++r) {
        size_t m = m0 + wr + mi * 16 + kg * 4 + r;
        size_t n = n0 + wc + ni * 16 + qr;
        float v = acc[mi][ni][r];
        if (MODE == 0)
          Cf[m * (size_t)N + n] = v;
        else if (MODE == 1)
          Cb[m * (size_t)N + n] = f2b(v);
        else
          Cb[((m >> 11) << 22) + (n << 11) + (m & 2047)] = f2b(v);
      }
    }
  }
}

// ---------------- flash attention ----------------
// Q,K: [B,L,D] bf16 (Q pre-scaled); V: Vt[b,h,d,l] bf16; O: [B,L,D] bf16
// grid (L/64, B*H), 256 threads = 4 waves, 16 q-rows per wave, KVBLK=32
__global__ __launch_bounds__(256) void attn_k(const u16* __restrict__ Q,
                                              const u16* __restrict__ K,
                                              const u16* __restrict__ V,
                                              u16* __restrict__ O) {
  __shared__ u16 pbuf[4][16 * 40];  // wave-private, padded (bank-spread)
  const int tid = threadIdx.x;
  const int lane = tid & 63;
  const int w = tid >> 6;
  const int qr = lane & 15;
  const int kg = lane >> 4;
  const int bh = blockIdx.y;
  const size_t bbase = (size_t)(bh >> 4) * (2048 * 2048);
  const int hoff = (bh & 15) * 128;
  const int q0 = blockIdx.x * 64 + w * 16;

  const u16* Qrow = Q + bbase + (size_t)(q0 + qr) * 2048 + hoff;
  const u16* Kh = K + bbase + hoff;
  const u16* Vh = V + ((size_t)bh << 18);

  s16x8 aq[4];
#pragma unroll
  for (int c = 0; c < 4; ++c) aq[c] = *(const s16x8*)(Qrow + c * 32 + kg * 8);

  f32x4 o[8] = {};
  float mrow[4] = {-1e30f, -1e30f, -1e30f, -1e30f};
  float lrow[4] = {0.f, 0.f, 0.f, 0.f};
  u16* pb = pbuf[w];

  for (int k0 = 0; k0 < 2048; k0 += 32) {
    f32x4 st[2];
#pragma unroll
    for (int kt = 0; kt < 2; ++kt) {
      const u16* Krow = Kh + (size_t)(k0 + kt * 16 + qr) * 2048;
      f32x4 a = {0.f, 0.f, 0.f, 0.f};
#pragma unroll
      for (int c = 0; c < 4; ++c) {
        s16x8 bk = *(const s16x8*)(Krow + c * 32 + kg * 8);
        a = MFMA16(aq[c], bk, a);
      }
      st[kt] = a;
    }
    // online softmax: row stats live per-lane for rows kg*4+r
    float cf[4];
#pragma unroll
    for (int r = 0; r < 4; ++r) {
      float v = fmaxf(st[0][r], st[1][r]);
#pragma unroll
      for (int off = 1; off < 16; off <<= 1) v = fmaxf(v, __shfl_xor(v, off, 64));
      float mn = fmaxf(mrow[r], v);
      cf[r] = __expf(mrow[r] - mn);
      mrow[r] = mn;
      float p0 = __expf(st[0][r] - mn);
      float p1 = __expf(st[1][r] - mn);
      st[0][r] = p0; st[1][r] = p1;
      float ps = p0 + p1;
#pragma unroll
      for (int off = 1; off < 16; off <<= 1) ps += __shfl_xor(ps, off, 64);
      lrow[r] = lrow[r] * cf[r] + ps;
    }
    // P (C-layout) -> LDS -> A-layout fragment (wave-private, no barrier)
#pragma unroll
    for (int kt = 0; kt < 2; ++kt)
#pragma unroll
      for (int r = 0; r < 4; ++r)
        pb[(kg * 4 + r) * 40 + kt * 16 + qr] = f2b(st[kt][r]);
#pragma unroll
    for (int dt = 0; dt < 8; ++dt)
#pragma unroll
      for (int r = 0; r < 4; ++r) o[dt][r] *= cf[r];
    s16x8 pa = *(const s16x8*)(pb + qr * 40 + kg * 8);
#pragma unroll
    for (int dt = 0; dt < 8; ++dt) {
      s16x8 bv = *(const s16x8*)(Vh + (size_t)(dt * 16 + qr) * 2048 + k0 + kg * 8);
      o[dt] = MFMA16(pa, bv, o[dt]);
    }
  }

  u16* Ob = O + bbase + hoff;
#pragma unroll
  for (int r = 0; r < 4; ++r) {
    float inv = 1.0f / lrow[r];
    u16* orow = Ob + (size_t)(q0 + kg * 4 + r) * 2048;
#pragma unroll
    for (int dt = 0; dt < 8; ++dt) orow[dt * 16 + qr] = f2b(o[dt][r] * inv);
  }
}

// ---------------- confidence head: logits = out . Wc; conf = sigmoid ----------------
__global__ __launch_bounds__(256) void conf_k(const float* __restrict__ out,
                                              const float* __restrict__ Wc,
                                              float* __restrict__ conf,
                                              float* __restrict__ logits) {
  int row = blockIdx.x * 4 + (threadIdx.x >> 6);  // 4096 rows
  int lane = threadIdx.x & 63;
  const float* r = out + (size_t)row * 2048;
  float sum = 0.f;
#pragma unroll
  for (int j = 0; j < 8; ++j) {
    int i = (j * 64 + lane) * 4;
    float4 a = *(const float4*)(r + i);
    float4 b = *(const float4*)(Wc + i);
    sum += a.x * b.x + a.y * b.y + a.z * b.z + a.w * b.w;
  }
#pragma unroll
  for (int off = 1; off < 64; off <<= 1) sum += __shfl_xor(sum, off, 64);
  if (lane == 0) {
    logits[row] = sum;
    conf[row] = 1.0f / (1.0f + __expf(-sum));
  }
}

extern "C" void kernel_launch(void* const* d_in, const int* in_sizes, int n_in,
                              void* d_out, int out_size, void* d_ws, size_t ws_size,
                              hipStream_t stream) {
  const float* x = (const float*)d_in[0];
  const float* Wq = (const float*)d_in[1];
  const float* Wk = (const float*)d_in[2];
  const float* Wv = (const float*)d_in[3];
  const float* Wo = (const float*)d_in[4];
  const float* Wc = (const float*)d_in[5];
  float* out = (float*)d_out;

  char* ws = (char*)d_ws;
  u16* xb  = (u16*)(ws + 0);           // 16 MB; reused as attention-out later
  u16* Wqb = (u16*)(ws + 16777216);    // 8 MB; reused for Wo later
  u16* Wkb = (u16*)(ws + 25165824);    // 8 MB
  u16* Wvb = (u16*)(ws + 33554432);    // 8 MB
  u16* Qb  = (u16*)(ws + 41943040);    // 16 MB
  u16* Kb  = (u16*)(ws + 58720256);    // 16 MB
  u16* Vt  = (u16*)(ws + 75497472);    // 16 MB
  float2* tbl = (float2*)(ws + 92274688);  // 1 MB

  cvt_f32_bf16<<<8192, 256, 0, stream>>>(x, xb, 2097152);
  cvt_f32_bf16<<<4096, 256, 0, stream>>>(Wq, Wqb, 1048576);
  cvt_f32_bf16<<<4096, 256, 0, stream>>>(Wk, Wkb, 1048576);
  cvt_f32_bf16<<<4096, 256, 0, stream>>>(Wv, Wvb, 1048576);
  rope_table_k<<<512, 256, 0, stream>>>(tbl);

  gemm_nt<1><<<dim3(16, 32), 256, 0, stream>>>(xb, Wqb, nullptr, Qb, 4096, 2048, 2048);
  gemm_nt<1><<<dim3(16, 32), 256, 0, stream>>>(xb, Wkb, nullptr, Kb, 4096, 2048, 2048);
  gemm_nt<2><<<dim3(16, 32), 256, 0, stream>>>(xb, Wvb, nullptr, Vt, 4096, 2048, 2048);

  cvt_f32_bf16<<<4096, 256, 0, stream>>>(Wo, Wqb, 1048576);  // after Q GEMM retired

  rope_apply_k<<<4096, 256, 0, stream>>>(Qb, Kb, tbl, 0.08838834764831845f);

  attn_k<<<dim3(32, 32), 256, 0, stream>>>(Qb, Kb, Vt, xb);  // xb now holds attn out

  gemm_nt<0><<<dim3(16, 32), 256, 0, stream>>>(xb, Wqb, out, nullptr, 4096, 2048, 2048);

  conf_k<<<1024, 256, 0, stream>>>(out, Wc, out + 8388608, out + 8392704);
}

// Round 4
// 555.447 us; speedup vs baseline: 1.4736x; 1.4736x over previous
//
#include <hip/hip_runtime.h>

typedef unsigned short u16;
typedef short s16x8 __attribute__((ext_vector_type(8)));
typedef u16 u16x8 __attribute__((ext_vector_type(8)));
typedef u16 u16x4 __attribute__((ext_vector_type(4)));
typedef float f32x4 __attribute__((ext_vector_type(4)));

#define MFMA16(A, B, C) __builtin_amdgcn_mfma_f32_16x16x32_bf16(A, B, C, 0, 0, 0)
#define GLOAD_LDS16(g, l) \
  __builtin_amdgcn_global_load_lds((const __attribute__((address_space(1))) void*)(g), \
                                   (__attribute__((address_space(3))) void*)(l), 16, 0, 0)

__device__ __forceinline__ u16 f2b(float f) {
  union { float f; unsigned u; } v; v.f = f;
  unsigned r = v.u + 0x7fffu + ((v.u >> 16) & 1u);
  return (u16)(r >> 16);
}
__device__ __forceinline__ float b2f(u16 u) {
  union { unsigned u; float f; } v; v.u = ((unsigned)u) << 16;
  return v.f;
}

// ---------------- fp32 -> bf16 convert (vectorized) ----------------
__global__ __launch_bounds__(256) void cvt_f32_bf16(const float* __restrict__ src,
                                                    u16* __restrict__ dst, int n4) {
  int i = blockIdx.x * 256 + threadIdx.x;
  if (i >= n4) return;
  float4 v = ((const float4*)src)[i];
  u16x4 o;
  o[0] = f2b(v.x); o[1] = f2b(v.y); o[2] = f2b(v.z); o[3] = f2b(v.w);
  ((u16x4*)dst)[i] = o;
}

// ---------------- RoPE cos/sin table: [2048][64] float2 ----------------
__global__ __launch_bounds__(256) void rope_table_k(float2* __restrict__ tbl) {
  int t = blockIdx.x * 256 + threadIdx.x;  // 131072 total
  int l = t >> 6, d = t & 63;
  float freq = exp2f(-0.20762050593045952f * (float)d);  // 10000^(-d/64)
  float a = (float)l * freq;
  float s, c;
  sincosf(a, &s, &c);
  tbl[t] = make_float2(c, s);
}

// ---------------- RoPE apply in-place on Q and K ([B,L,D] bf16) ----------------
__global__ __launch_bounds__(256) void rope_apply_k(u16* __restrict__ Q, u16* __restrict__ K,
                                                    const float2* __restrict__ tbl,
                                                    float qscale) {
  int t = blockIdx.x * 256 + threadIdx.x;  // 1,048,576 total
  int tensor = t >> 19;
  int idx = t & 524287;
  int g = idx & 7;           // d-group: d0 = g*8 in [0,64)
  int rest = idx >> 3;       // b*32768 + l*16 + h
  int h = rest & 15;
  int l = (rest >> 4) & 2047;
  int b = rest >> 15;
  u16* base = (tensor ? K : Q) + (((size_t)(b * 2048 + l)) << 11) + h * 128 + g * 8;
  float sc = tensor ? 1.0f : qscale;
  u16x8 v1 = *(const u16x8*)base;        // d..d+8
  u16x8 v2 = *(const u16x8*)(base + 64); // d+64..d+72
  const float2* cs = tbl + l * 64 + g * 8;
  u16x8 o1, o2;
#pragma unroll
  for (int j = 0; j < 8; ++j) {
    float a = b2f((u16)v1[j]), bb = b2f((u16)v2[j]);
    float c = cs[j].x, s = cs[j].y;
    o1[j] = f2b((a * c - bb * s) * sc);
    o2[j] = f2b((bb * c + a * s) * sc);
  }
  *(u16x8*)base = o1;
  *(u16x8*)(base + 64) = o2;
}

// ---------------- bf16 NT GEMM: C[m,n] = sum_k A[m,k]*B[n,k] ----------------
// MODE 0: fp32 row-major out; MODE 1: bf16 row-major out; MODE 2: bf16 V^T out
template <int MODE>
__global__ __launch_bounds__(256, 2) void gemm_nt(const u16* __restrict__ A,
                                                  const u16* __restrict__ B,
                                                  float* __restrict__ Cf,
                                                  u16* __restrict__ Cb,
                                                  int M, int N, int K) {
  __shared__ u16 sA[128 * 64];
  __shared__ u16 sB[128 * 64];
  const int tid = threadIdx.x;
  const int lane = tid & 63;
  const int w = tid >> 6;
  const int wr = (w >> 1) * 64;
  const int wc = (w & 1) * 64;
  const int qr = lane & 15;
  const int kg = lane >> 4;
  const size_t m0 = (size_t)blockIdx.y * 128;
  const size_t n0 = (size_t)blockIdx.x * 128;

  f32x4 acc[4][4] = {};

  for (int k0 = 0; k0 < K; k0 += 64) {
#pragma unroll
    for (int j = 0; j < 4; ++j) {
      int i = j * 256 + tid;
      const u16* ga = A + (m0 + (i >> 3)) * (size_t)K + k0 + (i & 7) * 8;
      GLOAD_LDS16(ga, sA + i * 8);
    }
#pragma unroll
    for (int j = 0; j < 4; ++j) {
      int i = j * 256 + tid;
      const u16* gb = B + (n0 + (i >> 3)) * (size_t)K + k0 + (i & 7) * 8;
      GLOAD_LDS16(gb, sB + i * 8);
    }
    __syncthreads();  // drains vmcnt(0) before LDS reads
#pragma unroll
    for (int kk = 0; kk < 2; ++kk) {
      const int ko = kk * 32 + kg * 8;
      s16x8 af[4], bfr[4];
#pragma unroll
      for (int mi = 0; mi < 4; ++mi)
        af[mi] = *(const s16x8*)(sA + (wr + mi * 16 + qr) * 64 + ko);
#pragma unroll
      for (int ni = 0; ni < 4; ++ni)
        bfr[ni] = *(const s16x8*)(sB + (wc + ni * 16 + qr) * 64 + ko);
#pragma unroll
      for (int mi = 0; mi < 4; ++mi)
#pragma unroll
        for (int ni = 0; ni < 4; ++ni)
          acc[mi][ni] = MFMA16(af[mi], bfr[ni], acc[mi][ni]);
    }
    __syncthreads();
  }

#pragma unroll
  for (int mi = 0; mi < 4; ++mi) {
#pragma unroll
    for (int ni = 0; ni < 4; ++ni) {
#pragma unroll
      for (int r = 0; r < 4; ++r) {
        size_t m = m0 + wr + mi * 16 + kg * 4 + r;
        size_t n = n0 + wc + ni * 16 + qr;
        float v = acc[mi][ni][r];
        if (MODE == 0)
          Cf[m * (size_t)N + n] = v;
        else if (MODE == 1)
          Cb[m * (size_t)N + n] = f2b(v);
        else
          Cb[((m >> 11) << 22) + (n << 11) + (m & 2047)] = f2b(v);
      }
    }
  }
}

// ---------------- flash attention, LDS-staged K/V ----------------
// Q,K: [B,L,D] bf16 (Q pre-scaled); V: Vt[b,h,d,l] bf16; O: [B,L,D] bf16
// grid (L/64, B*H), 256 threads = 4 waves, 16 q-rows/wave, KVBLK=64.
// K-tile [64][128] and Vt-tile [128][64] staged via global_load_lds with
// XOR swizzle (chunk ^= row&7) applied on the GLOBAL source address
// (linear LDS dest) and on the ds_read address — rule #21.
__global__ __launch_bounds__(256) void attn_k(const u16* __restrict__ Q,
                                              const u16* __restrict__ K,
                                              const u16* __restrict__ V,
                                              u16* __restrict__ O) {
  __shared__ u16 sK[64 * 128];   // 16 KB
  __shared__ u16 sV[128 * 64];   // 16 KB
  __shared__ u16 pbuf[4][16 * 72];  // wave-private P bounce, 9 KB
  const int tid = threadIdx.x;
  const int lane = tid & 63;
  const int w = tid >> 6;
  const int qr = lane & 15;
  const int kg = lane >> 4;
  const int bh = blockIdx.y;
  const size_t bbase = (size_t)(bh >> 4) * (2048 * 2048);
  const int hoff = (bh & 15) * 128;
  const int q0 = blockIdx.x * 64 + w * 16;

  const u16* Qrow = Q + bbase + (size_t)(q0 + qr) * 2048 + hoff;
  const u16* Kh = K + bbase + hoff;
  const u16* Vh = V + ((size_t)bh << 18);

  s16x8 aq[4];
#pragma unroll
  for (int c = 0; c < 4; ++c) aq[c] = *(const s16x8*)(Qrow + c * 32 + kg * 8);

  f32x4 o[8] = {};
  float mrow[4] = {-1e30f, -1e30f, -1e30f, -1e30f};
  float lrow[4] = {0.f, 0.f, 0.f, 0.f};
  u16* pb = pbuf[w];

  for (int k0 = 0; k0 < 2048; k0 += 64) {
    // stage K-tile: 1024 chunks of 16B, linear LDS dest, swizzled source
#pragma unroll
    for (int j = 0; j < 4; ++j) {
      int c = j * 256 + tid;
      int r = c >> 4, sc = c & 15;
      const u16* g = Kh + (size_t)(k0 + r) * 2048 + ((sc ^ (r & 7)) << 3);
      GLOAD_LDS16(g, sK + c * 8);
    }
    // stage Vt-tile: rows = d (128), cols = k0..k0+64
#pragma unroll
    for (int j = 0; j < 4; ++j) {
      int c = j * 256 + tid;
      int r = c >> 3, sc = c & 7;
      const u16* g = Vh + ((size_t)r << 11) + k0 + ((sc ^ (r & 7)) << 3);
      GLOAD_LDS16(g, sV + c * 8);
    }
    __syncthreads();

    // QK^T: 4 k-subtiles of 16
    f32x4 st[4];
#pragma unroll
    for (int kt = 0; kt < 4; ++kt) {
      int rn = kt * 16 + qr;
      f32x4 a = {0.f, 0.f, 0.f, 0.f};
#pragma unroll
      for (int c = 0; c < 4; ++c) {
        int cc = c * 4 + kg;
        s16x8 bk = *(const s16x8*)(sK + rn * 128 + ((cc ^ (rn & 7)) << 3));
        a = MFMA16(aq[c], bk, a);
      }
      st[kt] = a;
    }

    // online softmax: per lane rows kg*4+r, cols qr + 16*kt
    float cf[4];
#pragma unroll
    for (int r = 0; r < 4; ++r) {
      float v = fmaxf(fmaxf(st[0][r], st[1][r]), fmaxf(st[2][r], st[3][r]));
#pragma unroll
      for (int off = 1; off < 16; off <<= 1) v = fmaxf(v, __shfl_xor(v, off, 64));
      float mn = fmaxf(mrow[r], v);
      cf[r] = __expf(mrow[r] - mn);
      mrow[r] = mn;
      float ps = 0.f;
#pragma unroll
      for (int kt = 0; kt < 4; ++kt) {
        float p = __expf(st[kt][r] - mn);
        st[kt][r] = p;
        ps += p;
      }
#pragma unroll
      for (int off = 1; off < 16; off <<= 1) ps += __shfl_xor(ps, off, 64);
      lrow[r] = lrow[r] * cf[r] + ps;
    }

    // P (C-layout) -> LDS -> A-layout fragments (wave-private)
#pragma unroll
    for (int kt = 0; kt < 4; ++kt)
#pragma unroll
      for (int r = 0; r < 4; ++r)
        pb[(kg * 4 + r) * 72 + kt * 16 + qr] = f2b(st[kt][r]);
#pragma unroll
    for (int dt = 0; dt < 8; ++dt)
#pragma unroll
      for (int r = 0; r < 4; ++r) o[dt][r] *= cf[r];

    s16x8 pa0 = *(const s16x8*)(pb + qr * 72 + kg * 8);
    s16x8 pa1 = *(const s16x8*)(pb + qr * 72 + 32 + kg * 8);
#pragma unroll
    for (int dt = 0; dt < 8; ++dt) {
      int n = dt * 16 + qr;
      s16x8 bv0 = *(const s16x8*)(sV + n * 64 + ((kg ^ (n & 7)) << 3));
      s16x8 bv1 = *(const s16x8*)(sV + n * 64 + (((4 + kg) ^ (n & 7)) << 3));
      o[dt] = MFMA16(pa0, bv0, o[dt]);
      o[dt] = MFMA16(pa1, bv1, o[dt]);
    }
    __syncthreads();
  }

  u16* Ob = O + bbase + hoff;
#pragma unroll
  for (int r = 0; r < 4; ++r) {
    float inv = 1.0f / lrow[r];
    u16* orow = Ob + (size_t)(q0 + kg * 4 + r) * 2048;
#pragma unroll
    for (int dt = 0; dt < 8; ++dt) orow[dt * 16 + qr] = f2b(o[dt][r] * inv);
  }
}

// ---------------- confidence head: logits = out . Wc; conf = sigmoid ----------------
__global__ __launch_bounds__(256) void conf_k(const float* __restrict__ out,
                                              const float* __restrict__ Wc,
                                              float* __restrict__ conf,
                                              float* __restrict__ logits) {
  int row = blockIdx.x * 4 + (threadIdx.x >> 6);  // 4096 rows
  int lane = threadIdx.x & 63;
  const float* r = out + (size_t)row * 2048;
  float sum = 0.f;
#pragma unroll
  for (int j = 0; j < 8; ++j) {
    int i = (j * 64 + lane) * 4;
    float4 a = *(const float4*)(r + i);
    float4 b = *(const float4*)(Wc + i);
    sum += a.x * b.x + a.y * b.y + a.z * b.z + a.w * b.w;
  }
#pragma unroll
  for (int off = 1; off < 64; off <<= 1) sum += __shfl_xor(sum, off, 64);
  if (lane == 0) {
    logits[row] = sum;
    conf[row] = 1.0f / (1.0f + __expf(-sum));
  }
}

extern "C" void kernel_launch(void* const* d_in, const int* in_sizes, int n_in,
                              void* d_out, int out_size, void* d_ws, size_t ws_size,
                              hipStream_t stream) {
  const float* x = (const float*)d_in[0];
  const float* Wq = (const float*)d_in[1];
  const float* Wk = (const float*)d_in[2];
  const float* Wv = (const float*)d_in[3];
  const float* Wo = (const float*)d_in[4];
  const float* Wc = (const float*)d_in[5];
  float* out = (float*)d_out;

  char* ws = (char*)d_ws;
  u16* xb  = (u16*)(ws + 0);           // 16 MB; reused as attention-out later
  u16* Wqb = (u16*)(ws + 16777216);    // 8 MB; reused for Wo later
  u16* Wkb = (u16*)(ws + 25165824);    // 8 MB
  u16* Wvb = (u16*)(ws + 33554432);    // 8 MB
  u16* Qb  = (u16*)(ws + 41943040);    // 16 MB
  u16* Kb  = (u16*)(ws + 58720256);    // 16 MB
  u16* Vt  = (u16*)(ws + 75497472);    // 16 MB
  float2* tbl = (float2*)(ws + 92274688);  // 1 MB

  cvt_f32_bf16<<<8192, 256, 0, stream>>>(x, xb, 2097152);
  cvt_f32_bf16<<<4096, 256, 0, stream>>>(Wq, Wqb, 1048576);
  cvt_f32_bf16<<<4096, 256, 0, stream>>>(Wk, Wkb, 1048576);
  cvt_f32_bf16<<<4096, 256, 0, stream>>>(Wv, Wvb, 1048576);
  rope_table_k<<<512, 256, 0, stream>>>(tbl);

  gemm_nt<1><<<dim3(16, 32), 256, 0, stream>>>(xb, Wqb, nullptr, Qb, 4096, 2048, 2048);
  gemm_nt<1><<<dim3(16, 32), 256, 0, stream>>>(xb, Wkb, nullptr, Kb, 4096, 2048, 2048);
  gemm_nt<2><<<dim3(16, 32), 256, 0, stream>>>(xb, Wvb, nullptr, Vt, 4096, 2048, 2048);

  cvt_f32_bf16<<<4096, 256, 0, stream>>>(Wo, Wqb, 1048576);  // after Q GEMM retired

  rope_apply_k<<<4096, 256, 0, stream>>>(Qb, Kb, tbl, 0.08838834764831845f);

  attn_k<<<dim3(32, 32), 256, 0, stream>>>(Qb, Kb, Vt, xb);  // xb now holds attn out

  gemm_nt<0><<<dim3(16, 32), 256, 0, stream>>>(xb, Wqb, out, nullptr, 4096, 2048, 2048);

  conf_k<<<1024, 256, 0, stream>>>(out, Wc, out + 8388608, out + 8392704);
}

// Round 5
// 548.037 us; speedup vs baseline: 1.4935x; 1.0135x over previous
//
#include <hip/hip_runtime.h>

typedef unsigned short u16;
typedef short s16x8 __attribute__((ext_vector_type(8)));
typedef u16 u16x8 __attribute__((ext_vector_type(8)));
typedef u16 u16x4 __attribute__((ext_vector_type(4)));
typedef float f32x4 __attribute__((ext_vector_type(4)));

#define MFMA16(A, B, C) __builtin_amdgcn_mfma_f32_16x16x32_bf16(A, B, C, 0, 0, 0)
#define GLOAD_LDS16(g, l) \
  __builtin_amdgcn_global_load_lds((const __attribute__((address_space(1))) void*)(g), \
                                   (__attribute__((address_space(3))) void*)(l), 16, 0, 0)

__device__ __forceinline__ u16 f2b(float f) {
  union { float f; unsigned u; } v; v.f = f;
  unsigned r = v.u + 0x7fffu + ((v.u >> 16) & 1u);
  return (u16)(r >> 16);
}
__device__ __forceinline__ float b2f(u16 u) {
  union { unsigned u; float f; } v; v.u = ((unsigned)u) << 16;
  return v.f;
}

// ---------------- fp32 -> bf16 convert (vectorized) ----------------
__global__ __launch_bounds__(256) void cvt_f32_bf16(const float* __restrict__ src,
                                                    u16* __restrict__ dst, int n4) {
  int i = blockIdx.x * 256 + threadIdx.x;
  if (i >= n4) return;
  float4 v = ((const float4*)src)[i];
  u16x4 o;
  o[0] = f2b(v.x); o[1] = f2b(v.y); o[2] = f2b(v.z); o[3] = f2b(v.w);
  ((u16x4*)dst)[i] = o;
}

// ---------------- RoPE cos/sin table: [2048][64] float2 ----------------
__global__ __launch_bounds__(256) void rope_table_k(float2* __restrict__ tbl) {
  int t = blockIdx.x * 256 + threadIdx.x;  // 131072 total
  int l = t >> 6, d = t & 63;
  float freq = exp2f(-0.20762050593045952f * (float)d);  // 10000^(-d/64)
  float a = (float)l * freq;
  float s, c;
  sincosf(a, &s, &c);
  tbl[t] = make_float2(c, s);
}

// ---------------- RoPE apply in-place on Q and K ([B,L,D] bf16) ----------------
// Q additionally scaled by qscale = hd^-0.5 * log2(e)  (attn works in exp2 domain)
__global__ __launch_bounds__(256) void rope_apply_k(u16* __restrict__ Q, u16* __restrict__ K,
                                                    const float2* __restrict__ tbl,
                                                    float qscale) {
  int t = blockIdx.x * 256 + threadIdx.x;  // 1,048,576 total
  int tensor = t >> 19;
  int idx = t & 524287;
  int g = idx & 7;           // d-group: d0 = g*8 in [0,64)
  int rest = idx >> 3;       // b*32768 + l*16 + h
  int h = rest & 15;
  int l = (rest >> 4) & 2047;
  int b = rest >> 15;
  u16* base = (tensor ? K : Q) + (((size_t)(b * 2048 + l)) << 11) + h * 128 + g * 8;
  float sc = tensor ? 1.0f : qscale;
  u16x8 v1 = *(const u16x8*)base;        // d..d+8
  u16x8 v2 = *(const u16x8*)(base + 64); // d+64..d+72
  const float2* cs = tbl + l * 64 + g * 8;
  u16x8 o1, o2;
#pragma unroll
  for (int j = 0; j < 8; ++j) {
    float a = b2f((u16)v1[j]), bb = b2f((u16)v2[j]);
    float c = cs[j].x, s = cs[j].y;
    o1[j] = f2b((a * c - bb * s) * sc);
    o2[j] = f2b((bb * c + a * s) * sc);
  }
  *(u16x8*)base = o1;
  *(u16x8*)(base + 64) = o2;
}

// ---------------- bf16 NT GEMM: C[m,n] = sum_k A[m,k]*B[n,k] ----------------
// MODE 0: fp32 row-major out; MODE 1: bf16 row-major out; MODE 2: bf16 V^T out
// Grid fixed at (16,32) = 512 blocks; XCD-aware bijective swizzle (512 = 8*64).
template <int MODE>
__global__ __launch_bounds__(256, 2) void gemm_nt(const u16* __restrict__ A,
                                                  const u16* __restrict__ B,
                                                  float* __restrict__ Cf,
                                                  u16* __restrict__ Cb,
                                                  int M, int N, int K) {
  __shared__ u16 sA[128 * 64];
  __shared__ u16 sB[128 * 64];
  const int tid = threadIdx.x;
  const int lane = tid & 63;
  const int w = tid >> 6;
  const int wr = (w >> 1) * 64;
  const int wc = (w & 1) * 64;
  const int qr = lane & 15;
  const int kg = lane >> 4;
  int orig = blockIdx.y * 16 + blockIdx.x;            // 0..511
  int swz = ((orig & 7) << 6) | (orig >> 3);          // XCD chunking (T1)
  const size_t m0 = (size_t)(swz >> 4) * 128;
  const size_t n0 = (size_t)(swz & 15) * 128;

  f32x4 acc[4][4] = {};

  for (int k0 = 0; k0 < K; k0 += 64) {
#pragma unroll
    for (int j = 0; j < 4; ++j) {
      int i = j * 256 + tid;
      const u16* ga = A + (m0 + (i >> 3)) * (size_t)K + k0 + (i & 7) * 8;
      GLOAD_LDS16(ga, sA + i * 8);
    }
#pragma unroll
    for (int j = 0; j < 4; ++j) {
      int i = j * 256 + tid;
      const u16* gb = B + (n0 + (i >> 3)) * (size_t)K + k0 + (i & 7) * 8;
      GLOAD_LDS16(gb, sB + i * 8);
    }
    __syncthreads();  // drains vmcnt(0) before LDS reads
#pragma unroll
    for (int kk = 0; kk < 2; ++kk) {
      const int ko = kk * 32 + kg * 8;
      s16x8 af[4], bfr[4];
#pragma unroll
      for (int mi = 0; mi < 4; ++mi)
        af[mi] = *(const s16x8*)(sA + (wr + mi * 16 + qr) * 64 + ko);
#pragma unroll
      for (int ni = 0; ni < 4; ++ni)
        bfr[ni] = *(const s16x8*)(sB + (wc + ni * 16 + qr) * 64 + ko);
#pragma unroll
      for (int mi = 0; mi < 4; ++mi)
#pragma unroll
        for (int ni = 0; ni < 4; ++ni)
          acc[mi][ni] = MFMA16(af[mi], bfr[ni], acc[mi][ni]);
    }
    __syncthreads();
  }

#pragma unroll
  for (int mi = 0; mi < 4; ++mi) {
#pragma unroll
    for (int ni = 0; ni < 4; ++ni) {
#pragma unroll
      for (int r = 0; r < 4; ++r) {
        size_t m = m0 + wr + mi * 16 + kg * 4 + r;
        size_t n = n0 + wc + ni * 16 + qr;
        float v = acc[mi][ni][r];
        if (MODE == 0)
          Cf[m * (size_t)N + n] = v;
        else if (MODE == 1)
          Cb[m * (size_t)N + n] = f2b(v);
        else
          Cb[((m >> 11) << 22) + (n << 11) + (m & 2047)] = f2b(v);
      }
    }
  }
}

// ---------------- flash attention, double-buffered LDS K/V ----------------
// Q,K: [B,L,D] bf16 (Q pre-scaled by hd^-0.5*log2e); V: Vt[b,h,d,l]; O: [B,L,D] bf16
// grid (L/64, B*H), 256 threads = 4 waves, 16 q-rows/wave, KVBLK=64.
// 2-phase pipeline: issue STAGE(next) -> s_waitcnt vmcnt(8) -> s_barrier ->
// compute current -> s_barrier (no vmcnt drain; prefetch stays in flight).
__global__ __launch_bounds__(256) void attn_k(const u16* __restrict__ Q,
                                              const u16* __restrict__ K,
                                              const u16* __restrict__ V,
                                              u16* __restrict__ O) {
  __shared__ u16 sK[2][64 * 128];   // 2 x 16 KB
  __shared__ u16 sV[2][128 * 64];   // 2 x 16 KB
  __shared__ u16 pbuf[4][16 * 72];  // wave-private P bounce, 9 KB
  const int tid = threadIdx.x;
  const int lane = tid & 63;
  const int w = tid >> 6;
  const int qr = lane & 15;
  const int kg = lane >> 4;
  const int bh = blockIdx.y;
  const size_t bbase = (size_t)(bh >> 4) * (2048 * 2048);
  const int hoff = (bh & 15) * 128;
  const int q0 = blockIdx.x * 64 + w * 16;

  const u16* Qrow = Q + bbase + (size_t)(q0 + qr) * 2048 + hoff;
  const u16* Kh = K + bbase + hoff;
  const u16* Vh = V + ((size_t)bh << 18);

  // per-thread staging addresses (swizzled source, linear LDS dest — rule #21)
  const u16* gKp[4];
  const u16* gVp[4];
#pragma unroll
  for (int j = 0; j < 4; ++j) {
    int c = j * 256 + tid;
    int rk = c >> 4, sck = c & 15;
    gKp[j] = Kh + (size_t)rk * 2048 + ((sck ^ (rk & 7)) << 3);
    int rv = c >> 3, scv = c & 7;
    gVp[j] = Vh + ((size_t)rv << 11) + ((scv ^ (rv & 7)) << 3);
  }

#define STAGE_KV(bsel, kof)                                                    \
  {                                                                            \
    _Pragma("unroll") for (int j = 0; j < 4; ++j)                              \
        GLOAD_LDS16(gKp[j] + (size_t)(kof) * 2048,                             \
                    sK[bsel] + (j * 256 + tid) * 8);                           \
    _Pragma("unroll") for (int j = 0; j < 4; ++j)                              \
        GLOAD_LDS16(gVp[j] + (kof), sV[bsel] + (j * 256 + tid) * 8);           \
  }

  s16x8 aq[4];
#pragma unroll
  for (int c = 0; c < 4; ++c) aq[c] = *(const s16x8*)(Qrow + c * 32 + kg * 8);

  f32x4 o[8] = {};
  float mrow[4] = {-1e30f, -1e30f, -1e30f, -1e30f};
  float lrow[4] = {0.f, 0.f, 0.f, 0.f};
  u16* pb = pbuf[w];

  STAGE_KV(0, 0);
  int buf = 0;

  for (int k0 = 0; k0 < 2048; k0 += 64) {
    if (k0 + 64 < 2048) {
      STAGE_KV(buf ^ 1, k0 + 64);
      asm volatile("s_waitcnt vmcnt(8)" ::: "memory");  // current tile's 8 done
    } else {
      asm volatile("s_waitcnt vmcnt(0)" ::: "memory");
    }
    __builtin_amdgcn_s_barrier();
    const u16* sKb = sK[buf];
    const u16* sVb = sV[buf];

    // QK^T: 4 k-subtiles of 16
    f32x4 st[4];
#pragma unroll
    for (int kt = 0; kt < 4; ++kt) {
      int rn = kt * 16 + qr;
      f32x4 a = {0.f, 0.f, 0.f, 0.f};
#pragma unroll
      for (int c = 0; c < 4; ++c) {
        int cc = c * 4 + kg;
        s16x8 bk = *(const s16x8*)(sKb + rn * 128 + ((cc ^ (rn & 7)) << 3));
        a = MFMA16(aq[c], bk, a);
      }
      st[kt] = a;
    }

    // online softmax (exp2 domain), defer-max THR=8, per-lane partial sums
    float pmax[4];
#pragma unroll
    for (int r = 0; r < 4; ++r) {
      float v = fmaxf(fmaxf(st[0][r], st[1][r]), fmaxf(st[2][r], st[3][r]));
#pragma unroll
      for (int off = 1; off < 16; off <<= 1) v = fmaxf(v, __shfl_xor(v, off, 64));
      pmax[r] = v;
    }
    bool grow = (pmax[0] > mrow[0] + 8.f) || (pmax[1] > mrow[1] + 8.f) ||
                (pmax[2] > mrow[2] + 8.f) || (pmax[3] > mrow[3] + 8.f);
    if (__any(grow)) {
#pragma unroll
      for (int r = 0; r < 4; ++r) {
        float mn = fmaxf(mrow[r], pmax[r]);
        float cf = exp2f(mrow[r] - mn);
        mrow[r] = mn;
        lrow[r] *= cf;
#pragma unroll
        for (int dt = 0; dt < 8; ++dt) o[dt][r] *= cf;
      }
    }
#pragma unroll
    for (int r = 0; r < 4; ++r) {
      float lp = 0.f;
#pragma unroll
      for (int kt = 0; kt < 4; ++kt) {
        float p = exp2f(st[kt][r] - mrow[r]);
        st[kt][r] = p;
        lp += p;
      }
      lrow[r] += lp;
    }

    // P (C-layout) -> LDS -> A-layout fragments (wave-private)
#pragma unroll
    for (int kt = 0; kt < 4; ++kt)
#pragma unroll
      for (int r = 0; r < 4; ++r)
        pb[(kg * 4 + r) * 72 + kt * 16 + qr] = f2b(st[kt][r]);

    s16x8 pa0 = *(const s16x8*)(pb + qr * 72 + kg * 8);
    s16x8 pa1 = *(const s16x8*)(pb + qr * 72 + 32 + kg * 8);
#pragma unroll
    for (int dt = 0; dt < 8; ++dt) {
      int n = dt * 16 + qr;
      s16x8 bv0 = *(const s16x8*)(sVb + n * 64 + ((kg ^ (n & 7)) << 3));
      s16x8 bv1 = *(const s16x8*)(sVb + n * 64 + (((4 + kg) ^ (n & 7)) << 3));
      o[dt] = MFMA16(pa0, bv0, o[dt]);
      o[dt] = MFMA16(pa1, bv1, o[dt]);
    }
    __builtin_amdgcn_s_barrier();  // reads of buf done before next overwrite
    buf ^= 1;
  }

  // final cross-lane sum reduce (deferred out of the loop)
#pragma unroll
  for (int r = 0; r < 4; ++r) {
#pragma unroll
    for (int off = 1; off < 16; off <<= 1) lrow[r] += __shfl_xor(lrow[r], off, 64);
  }

  u16* Ob = O + bbase + hoff;
#pragma unroll
  for (int r = 0; r < 4; ++r) {
    float inv = 1.0f / lrow[r];
    u16* orow = Ob + (size_t)(q0 + kg * 4 + r) * 2048;
#pragma unroll
    for (int dt = 0; dt < 8; ++dt) orow[dt * 16 + qr] = f2b(o[dt][r] * inv);
  }
#undef STAGE_KV
}

// ---------------- confidence head: logits = out . Wc; conf = sigmoid ----------------
__global__ __launch_bounds__(256) void conf_k(const float* __restrict__ out,
                                              const float* __restrict__ Wc,
                                              float* __restrict__ conf,
                                              float* __restrict__ logits) {
  int row = blockIdx.x * 4 + (threadIdx.x >> 6);  // 4096 rows
  int lane = threadIdx.x & 63;
  const float* r = out + (size_t)row * 2048;
  float sum = 0.f;
#pragma unroll
  for (int j = 0; j < 8; ++j) {
    int i = (j * 64 + lane) * 4;
    float4 a = *(const float4*)(r + i);
    float4 b = *(const float4*)(Wc + i);
    sum += a.x * b.x + a.y * b.y + a.z * b.z + a.w * b.w;
  }
#pragma unroll
  for (int off = 1; off < 64; off <<= 1) sum += __shfl_xor(sum, off, 64);
  if (lane == 0) {
    logits[row] = sum;
    conf[row] = 1.0f / (1.0f + __expf(-sum));
  }
}

extern "C" void kernel_launch(void* const* d_in, const int* in_sizes, int n_in,
                              void* d_out, int out_size, void* d_ws, size_t ws_size,
                              hipStream_t stream) {
  const float* x = (const float*)d_in[0];
  const float* Wq = (const float*)d_in[1];
  const float* Wk = (const float*)d_in[2];
  const float* Wv = (const float*)d_in[3];
  const float* Wo = (const float*)d_in[4];
  const float* Wc = (const float*)d_in[5];
  float* out = (float*)d_out;

  char* ws = (char*)d_ws;
  u16* xb  = (u16*)(ws + 0);           // 16 MB; reused as attention-out later
  u16* Wqb = (u16*)(ws + 16777216);    // 8 MB; reused for Wo later
  u16* Wkb = (u16*)(ws + 25165824);    // 8 MB
  u16* Wvb = (u16*)(ws + 33554432);    // 8 MB
  u16* Qb  = (u16*)(ws + 41943040);    // 16 MB
  u16* Kb  = (u16*)(ws + 58720256);    // 16 MB
  u16* Vt  = (u16*)(ws + 75497472);    // 16 MB
  float2* tbl = (float2*)(ws + 92274688);  // 1 MB

  cvt_f32_bf16<<<8192, 256, 0, stream>>>(x, xb, 2097152);
  cvt_f32_bf16<<<4096, 256, 0, stream>>>(Wq, Wqb, 1048576);
  cvt_f32_bf16<<<4096, 256, 0, stream>>>(Wk, Wkb, 1048576);
  cvt_f32_bf16<<<4096, 256, 0, stream>>>(Wv, Wvb, 1048576);
  rope_table_k<<<512, 256, 0, stream>>>(tbl);

  gemm_nt<1><<<dim3(16, 32), 256, 0, stream>>>(xb, Wqb, nullptr, Qb, 4096, 2048, 2048);
  gemm_nt<1><<<dim3(16, 32), 256, 0, stream>>>(xb, Wkb, nullptr, Kb, 4096, 2048, 2048);
  gemm_nt<2><<<dim3(16, 32), 256, 0, stream>>>(xb, Wvb, nullptr, Vt, 4096, 2048, 2048);

  cvt_f32_bf16<<<4096, 256, 0, stream>>>(Wo, Wqb, 1048576);  // after Q GEMM retired

  // qscale = 128^-0.5 * log2(e): attention computes softmax in exp2 domain
  rope_apply_k<<<4096, 256, 0, stream>>>(Qb, Kb, tbl, 0.1275174093403682f);

  attn_k<<<dim3(32, 32), 256, 0, stream>>>(Qb, Kb, Vt, xb);  // xb now holds attn out

  gemm_nt<0><<<dim3(16, 32), 256, 0, stream>>>(xb, Wqb, out, nullptr, 4096, 2048, 2048);

  conf_k<<<1024, 256, 0, stream>>>(out, Wc, out + 8388608, out + 8392704);
}

// Round 8
// 493.611 us; speedup vs baseline: 1.6582x; 1.1103x over previous
//
#include <hip/hip_runtime.h>

typedef unsigned short u16;
typedef short s16x8 __attribute__((ext_vector_type(8)));
typedef u16 u16x8 __attribute__((ext_vector_type(8)));
typedef u16 u16x4 __attribute__((ext_vector_type(4)));
typedef float f32x4 __attribute__((ext_vector_type(4)));
typedef unsigned u32x4 __attribute__((ext_vector_type(4)));

#define MFMA16(A, B, C) __builtin_amdgcn_mfma_f32_16x16x32_bf16(A, B, C, 0, 0, 0)
#define GLOAD_LDS16(g, l) \
  __builtin_amdgcn_global_load_lds((const __attribute__((address_space(1))) void*)(g), \
                                   (__attribute__((address_space(3))) void*)(l), 16, 0, 0)

__device__ __forceinline__ u16 f2b(float f) {
  union { float f; unsigned u; } v; v.f = f;
  unsigned r = v.u + 0x7fffu + ((v.u >> 16) & 1u);
  return (u16)(r >> 16);
}
__device__ __forceinline__ float b2f(u16 u) {
  union { unsigned u; float f; } v; v.u = ((unsigned)u) << 16;
  return v.f;
}

// ---------------- fp32 -> bf16 convert (vectorized) ----------------
__global__ __launch_bounds__(256) void cvt_f32_bf16(const float* __restrict__ src,
                                                    u16* __restrict__ dst, int n4) {
  int i = blockIdx.x * 256 + threadIdx.x;
  if (i >= n4) return;
  float4 v = ((const float4*)src)[i];
  u16x4 o;
  o[0] = f2b(v.x); o[1] = f2b(v.y); o[2] = f2b(v.z); o[3] = f2b(v.w);
  ((u16x4*)dst)[i] = o;
}

// ---------------- RoPE cos/sin table: [2048][64] float2 ----------------
__global__ __launch_bounds__(256) void rope_table_k(float2* __restrict__ tbl) {
  int t = blockIdx.x * 256 + threadIdx.x;  // 131072 total
  int l = t >> 6, d = t & 63;
  float freq = exp2f(-0.20762050593045952f * (float)d);  // 10000^(-d/64)
  float a = (float)l * freq;
  float s, c;
  sincosf(a, &s, &c);
  tbl[t] = make_float2(c, s);
}

// ---------------- RoPE apply in-place on Q and K ([B,L,D] bf16) ----------------
// Q additionally scaled by qscale = hd^-0.5 * log2(e)  (attn works in exp2 domain)
__global__ __launch_bounds__(256) void rope_apply_k(u16* __restrict__ Q, u16* __restrict__ K,
                                                    const float2* __restrict__ tbl,
                                                    float qscale) {
  int t = blockIdx.x * 256 + threadIdx.x;  // 1,048,576 total
  int tensor = t >> 19;
  int idx = t & 524287;
  int g = idx & 7;           // d-group: d0 = g*8 in [0,64)
  int rest = idx >> 3;       // b*32768 + l*16 + h
  int h = rest & 15;
  int l = (rest >> 4) & 2047;
  int b = rest >> 15;
  u16* base = (tensor ? K : Q) + (((size_t)(b * 2048 + l)) << 11) + h * 128 + g * 8;
  float sc = tensor ? 1.0f : qscale;
  u16x8 v1 = *(const u16x8*)base;        // d..d+8
  u16x8 v2 = *(const u16x8*)(base + 64); // d+64..d+72
  const float2* cs = tbl + l * 64 + g * 8;
  u16x8 o1, o2;
#pragma unroll
  for (int j = 0; j < 8; ++j) {
    float a = b2f((u16)v1[j]), bb = b2f((u16)v2[j]);
    float c = cs[j].x, s = cs[j].y;
    o1[j] = f2b((a * c - bb * s) * sc);
    o2[j] = f2b((bb * c + a * s) * sc);
  }
  *(u16x8*)base = o1;
  *(u16x8*)(base + 64) = o2;
}

// ---------------- bf16 NT GEMM: C[m,n] = sum_k A[m,k]*B[n,k] ----------------
// MODE 0: fp32 row-major out; MODE 1: bf16 row-major out; MODE 2: bf16 V^T out
template <int MODE>
__global__ __launch_bounds__(256, 2) void gemm_nt(const u16* __restrict__ A,
                                                  const u16* __restrict__ B,
                                                  float* __restrict__ Cf,
                                                  u16* __restrict__ Cb,
                                                  int M, int N, int K) {
  __shared__ u16 sA[128 * 64];
  __shared__ u16 sB[128 * 64];
  const int tid = threadIdx.x;
  const int lane = tid & 63;
  const int w = tid >> 6;
  const int wr = (w >> 1) * 64;
  const int wc = (w & 1) * 64;
  const int qr = lane & 15;
  const int kg = lane >> 4;
  const size_t m0 = (size_t)blockIdx.y * 128;
  const size_t n0 = (size_t)blockIdx.x * 128;

  f32x4 acc[4][4] = {};

  for (int k0 = 0; k0 < K; k0 += 64) {
#pragma unroll
    for (int j = 0; j < 4; ++j) {
      int i = j * 256 + tid;
      const u16* ga = A + (m0 + (i >> 3)) * (size_t)K + k0 + (i & 7) * 8;
      GLOAD_LDS16(ga, sA + i * 8);
    }
#pragma unroll
    for (int j = 0; j < 4; ++j) {
      int i = j * 256 + tid;
      const u16* gb = B + (n0 + (i >> 3)) * (size_t)K + k0 + (i & 7) * 8;
      GLOAD_LDS16(gb, sB + i * 8);
    }
    __syncthreads();  // drains vmcnt(0) before LDS reads
#pragma unroll
    for (int kk = 0; kk < 2; ++kk) {
      const int ko = kk * 32 + kg * 8;
      s16x8 af[4], bfr[4];
#pragma unroll
      for (int mi = 0; mi < 4; ++mi)
        af[mi] = *(const s16x8*)(sA + (wr + mi * 16 + qr) * 64 + ko);
#pragma unroll
      for (int ni = 0; ni < 4; ++ni)
        bfr[ni] = *(const s16x8*)(sB + (wc + ni * 16 + qr) * 64 + ko);
#pragma unroll
      for (int mi = 0; mi < 4; ++mi)
#pragma unroll
        for (int ni = 0; ni < 4; ++ni)
          acc[mi][ni] = MFMA16(af[mi], bfr[ni], acc[mi][ni]);
    }
    __syncthreads();
  }

#pragma unroll
  for (int mi = 0; mi < 4; ++mi) {
#pragma unroll
    for (int ni = 0; ni < 4; ++ni) {
#pragma unroll
      for (int r = 0; r < 4; ++r) {
        size_t m = m0 + wr + mi * 16 + kg * 4 + r;
        size_t n = n0 + wc + ni * 16 + qr;
        float v = acc[mi][ni][r];
        if (MODE == 0)
          Cf[m * (size_t)N + n] = v;
        else if (MODE == 1)
          Cb[m * (size_t)N + n] = f2b(v);
        else
          Cb[((m >> 11) << 22) + (n << 11) + (m & 2047)] = f2b(v);
      }
    }
  }
}

// ---------------- flash attention v3: swapped QK^T, in-register P ----------------
// Q,K: [B,L,D] bf16 (Q pre-scaled by hd^-0.5*log2e); V: Vt[b,h,d,l]; O: [B,L,D] bf16
// grid (L/128, B*H), 512 threads = 8 waves, 16 q-rows/wave, KVBLK=64.
// QK^T computed as mfma(K,Q) so each lane holds a full slice of ONE q-row
// (reduction lane-local); P->bf16 via v_cvt_pk; PV A-frag built with shfl.
// LDS = 64KB (K/V double-buffered), no P bounce buffer => 2 blk/CU, 16 waves/CU.
__global__ __launch_bounds__(512, 4) void attn_k(const u16* __restrict__ Q,
                                                 const u16* __restrict__ K,
                                                 const u16* __restrict__ V,
                                                 u16* __restrict__ O) {
  __shared__ u16 sK[2][64 * 128];   // 2 x 16 KB
  __shared__ u16 sV[2][128 * 64];   // 2 x 16 KB
  const int tid = threadIdx.x;
  const int lane = tid & 63;
  const int w = tid >> 6;           // 0..7
  const int qr = lane & 15;
  const int kg = lane >> 4;
  const int bh = blockIdx.y;
  const size_t bbase = (size_t)(bh >> 4) * (2048 * 2048);
  const int hoff = (bh & 15) * 128;
  const int q0 = blockIdx.x * 128 + w * 16;

  const u16* Qrow = Q + bbase + (size_t)(q0 + qr) * 2048 + hoff;
  const u16* Kh = K + bbase + hoff;
  const u16* Vh = V + ((size_t)bh << 18);

  // per-thread staging element-offsets (swizzled source, linear LDS dest — rule #21)
  int kOff[2], vOff[2];
#pragma unroll
  for (int j = 0; j < 2; ++j) {
    int c = j * 512 + tid;
    int rk = c >> 4, sck = c & 15;
    kOff[j] = rk * 2048 + ((sck ^ (rk & 7)) << 3);
    int rv = c >> 3, scv = c & 7;
    vOff[j] = rv * 2048 + ((scv ^ (rv & 7)) << 3);
  }

#define STAGE_KV(bsel, kof)                                                    \
  {                                                                            \
    _Pragma("unroll") for (int j = 0; j < 2; ++j)                              \
        GLOAD_LDS16(Kh + (size_t)(kof) * 2048 + kOff[j],                       \
                    sK[bsel] + (j * 512 + tid) * 8);                           \
    _Pragma("unroll") for (int j = 0; j < 2; ++j)                              \
        GLOAD_LDS16(Vh + (kof) + vOff[j], sV[bsel] + (j * 512 + tid) * 8);     \
  }

  s16x8 aq[4];
#pragma unroll
  for (int c = 0; c < 4; ++c) aq[c] = *(const s16x8*)(Qrow + c * 32 + kg * 8);

  f32x4 o[8] = {};
  float mrow = -1e30f;   // running max for q-row qr (lane-local)
  float lrow = 0.f;      // partial sum for q-row qr over this lane's k-slice
  float mprev[4] = {-1e30f, -1e30f, -1e30f, -1e30f};  // last max for acc rows 4kg+r
  const int srcLo = qr + 32 * (kg & 1);  // P-redistribution source lanes
  const int srcHi = srcLo + 16;

  STAGE_KV(0, 0);
  int buf = 0;

  for (int k0 = 0; k0 < 2048; k0 += 64) {
    if (k0 + 64 < 2048) {
      STAGE_KV(buf ^ 1, k0 + 64);
      asm volatile("s_waitcnt vmcnt(4)" ::: "memory");  // current tile's 4 done
    } else {
      asm volatile("s_waitcnt vmcnt(0)" ::: "memory");
    }
    __builtin_amdgcn_s_barrier();
    const u16* sKb = sK[buf];
    const u16* sVb = sV[buf];

    // QK^T with SWAPPED operands: st[kt] lane(qr,kg) reg r = S[k=16kt+4kg+r][q=qr]
    f32x4 st[4];
#pragma unroll
    for (int kt = 0; kt < 4; ++kt) {
      int rn = kt * 16 + qr;
      f32x4 a = {0.f, 0.f, 0.f, 0.f};
#pragma unroll
      for (int c = 0; c < 4; ++c) {
        int cc = c * 4 + kg;
        s16x8 bk = *(const s16x8*)(sKb + rn * 128 + ((cc ^ (rn & 7)) << 3));
        a = MFMA16(bk, aq[c], a);
      }
      st[kt] = a;
    }

    // row-max: in-lane over 16 values, then 2 shfl rounds across kg groups
    float pm = fmaxf(fmaxf(fmaxf(st[0][0], st[0][1]), fmaxf(st[0][2], st[0][3])),
                     fmaxf(fmaxf(st[1][0], st[1][1]), fmaxf(st[1][2], st[1][3])));
    pm = fmaxf(pm,
               fmaxf(fmaxf(fmaxf(st[2][0], st[2][1]), fmaxf(st[2][2], st[2][3])),
                     fmaxf(fmaxf(st[3][0], st[3][1]), fmaxf(st[3][2], st[3][3]))));
    pm = fmaxf(pm, __shfl_xor(pm, 16, 64));
    pm = fmaxf(pm, __shfl_xor(pm, 32, 64));

    // defer-max (THR=8): rescale only when max grew meaningfully
    if (__any(pm > mrow + 8.f)) {
      float mnew = fmaxf(mrow, pm);
      lrow *= exp2f(mrow - mnew);
      mrow = mnew;
#pragma unroll
      for (int r = 0; r < 4; ++r) {
        float mnr = __shfl(mrow, kg * 4 + r, 64);  // new max for acc row 4kg+r
        float cfr = exp2f(mprev[r] - mnr);
        mprev[r] = mnr;
#pragma unroll
        for (int dt = 0; dt < 8; ++dt) o[dt][r] *= cfr;
      }
    }

    // P = exp2(S - m); pack adjacent-k pairs to bf16x2 via v_cvt_pk
    unsigned w2[8];
    float lsum = 0.f;
#pragma unroll
    for (int kt = 0; kt < 4; ++kt) {
      float p0 = exp2f(st[kt][0] - mrow), p1 = exp2f(st[kt][1] - mrow);
      float p2 = exp2f(st[kt][2] - mrow), p3 = exp2f(st[kt][3] - mrow);
      lsum += (p0 + p1) + (p2 + p3);
      asm("v_cvt_pk_bf16_f32 %0, %1, %2" : "=v"(w2[kt * 2]) : "v"(p0), "v"(p1));
      asm("v_cvt_pk_bf16_f32 %0, %1, %2" : "=v"(w2[kt * 2 + 1]) : "v"(p2), "v"(p3));
    }
    lrow += lsum;

    // redistribute P into PV A-fragments: lane(qr,kg) needs P[qr][32f+8kg+2jj+{0,1}]
    unsigned pw[8];
#pragma unroll
    for (int f = 0; f < 2; ++f) {
#pragma unroll
      for (int jj = 0; jj < 4; ++jj) {
        int src = (jj < 2) ? srcLo : srcHi;
        unsigned ra = (unsigned)__shfl((int)w2[4 * f + (jj & 1)], src, 64);
        unsigned rb = (unsigned)__shfl((int)w2[4 * f + 2 + (jj & 1)], src, 64);
        pw[f * 4 + jj] = (kg < 2) ? ra : rb;
      }
    }
    union { u32x4 u; s16x8 s; } ua, ub;
    ua.u = (u32x4){pw[0], pw[1], pw[2], pw[3]};
    ub.u = (u32x4){pw[4], pw[5], pw[6], pw[7]};

#pragma unroll
    for (int dt = 0; dt < 8; ++dt) {
      int n = dt * 16 + qr;
      s16x8 bv0 = *(const s16x8*)(sVb + n * 64 + ((kg ^ (n & 7)) << 3));
      s16x8 bv1 = *(const s16x8*)(sVb + n * 64 + (((4 + kg) ^ (n & 7)) << 3));
      o[dt] = MFMA16(ua.s, bv0, o[dt]);
      o[dt] = MFMA16(ub.s, bv1, o[dt]);
    }
    __builtin_amdgcn_s_barrier();  // reads of buf done before next overwrite
    buf ^= 1;
  }

  // combine l partials across kg groups; all lanes end with l[their qr]
  lrow += __shfl_xor(lrow, 16, 64);
  lrow += __shfl_xor(lrow, 32, 64);

  u16* Ob = O + bbase + hoff;
#pragma unroll
  for (int r = 0; r < 4; ++r) {
    float inv = 1.0f / __shfl(lrow, kg * 4 + r, 64);  // l for acc row 4kg+r
    u16* orow = Ob + (size_t)(q0 + kg * 4 + r) * 2048;
#pragma unroll
    for (int dt = 0; dt < 8; ++dt) orow[dt * 16 + qr] = f2b(o[dt][r] * inv);
  }
#undef STAGE_KV
}

// ---------------- confidence head: logits = out . Wc; conf = sigmoid ----------------
__global__ __launch_bounds__(256) void conf_k(const float* __restrict__ out,
                                              const float* __restrict__ Wc,
                                              float* __restrict__ conf,
                                              float* __restrict__ logits) {
  int row = blockIdx.x * 4 + (threadIdx.x >> 6);  // 4096 rows
  int lane = threadIdx.x & 63;
  const float* r = out + (size_t)row * 2048;
  float sum = 0.f;
#pragma unroll
  for (int j = 0; j < 8; ++j) {
    int i = (j * 64 + lane) * 4;
    float4 a = *(const float4*)(r + i);
    float4 b = *(const float4*)(Wc + i);
    sum += a.x * b.x + a.y * b.y + a.z * b.z + a.w * b.w;
  }
#pragma unroll
  for (int off = 1; off < 64; off <<= 1) sum += __shfl_xor(sum, off, 64);
  if (lane == 0) {
    logits[row] = sum;
    conf[row] = 1.0f / (1.0f + __expf(-sum));
  }
}

extern "C" void kernel_launch(void* const* d_in, const int* in_sizes, int n_in,
                              void* d_out, int out_size, void* d_ws, size_t ws_size,
                              hipStream_t stream) {
  const float* x = (const float*)d_in[0];
  const float* Wq = (const float*)d_in[1];
  const float* Wk = (const float*)d_in[2];
  const float* Wv = (const float*)d_in[3];
  const float* Wo = (const float*)d_in[4];
  const float* Wc = (const float*)d_in[5];
  float* out = (float*)d_out;

  char* ws = (char*)d_ws;
  u16* xb  = (u16*)(ws + 0);           // 16 MB; reused as attention-out later
  u16* Wqb = (u16*)(ws + 16777216);    // 8 MB; reused for Wo later
  u16* Wkb = (u16*)(ws + 25165824);    // 8 MB
  u16* Wvb = (u16*)(ws + 33554432);    // 8 MB
  u16* Qb  = (u16*)(ws + 41943040);    // 16 MB
  u16* Kb  = (u16*)(ws + 58720256);    // 16 MB
  u16* Vt  = (u16*)(ws + 75497472);    // 16 MB
  float2* tbl = (float2*)(ws + 92274688);  // 1 MB

  cvt_f32_bf16<<<8192, 256, 0, stream>>>(x, xb, 2097152);
  cvt_f32_bf16<<<4096, 256, 0, stream>>>(Wq, Wqb, 1048576);
  cvt_f32_bf16<<<4096, 256, 0, stream>>>(Wk, Wkb, 1048576);
  cvt_f32_bf16<<<4096, 256, 0, stream>>>(Wv, Wvb, 1048576);
  rope_table_k<<<512, 256, 0, stream>>>(tbl);

  gemm_nt<1><<<dim3(16, 32), 256, 0, stream>>>(xb, Wqb, nullptr, Qb, 4096, 2048, 2048);
  gemm_nt<1><<<dim3(16, 32), 256, 0, stream>>>(xb, Wkb, nullptr, Kb, 4096, 2048, 2048);
  gemm_nt<2><<<dim3(16, 32), 256, 0, stream>>>(xb, Wvb, nullptr, Vt, 4096, 2048, 2048);

  cvt_f32_bf16<<<4096, 256, 0, stream>>>(Wo, Wqb, 1048576);  // after Q GEMM retired

  // qscale = 128^-0.5 * log2(e): attention computes softmax in exp2 domain
  rope_apply_k<<<4096, 256, 0, stream>>>(Qb, Kb, tbl, 0.1275174093403682f);

  attn_k<<<dim3(16, 32), 512, 0, stream>>>(Qb, Kb, Vt, xb);  // xb now holds attn out

  gemm_nt<0><<<dim3(16, 32), 256, 0, stream>>>(xb, Wqb, out, nullptr, 4096, 2048, 2048);

  conf_k<<<1024, 256, 0, stream>>>(out, Wc, out + 8388608, out + 8392704);
}

// Round 9
// 484.606 us; speedup vs baseline: 1.6890x; 1.0186x over previous
//
#include <hip/hip_runtime.h>

typedef unsigned short u16;
typedef short s16x8 __attribute__((ext_vector_type(8)));
typedef u16 u16x8 __attribute__((ext_vector_type(8)));
typedef u16 u16x4 __attribute__((ext_vector_type(4)));
typedef float f32x4 __attribute__((ext_vector_type(4)));
typedef unsigned u32x4 __attribute__((ext_vector_type(4)));

#define MFMA16(A, B, C) __builtin_amdgcn_mfma_f32_16x16x32_bf16(A, B, C, 0, 0, 0)
#define GLOAD_LDS16(g, l) \
  __builtin_amdgcn_global_load_lds((const __attribute__((address_space(1))) void*)(g), \
                                   (__attribute__((address_space(3))) void*)(l), 16, 0, 0)

__device__ __forceinline__ u16 f2b(float f) {
  union { float f; unsigned u; } v; v.f = f;
  unsigned r = v.u + 0x7fffu + ((v.u >> 16) & 1u);
  return (u16)(r >> 16);
}
__device__ __forceinline__ float b2f(u16 u) {
  union { unsigned u; float f; } v; v.u = ((unsigned)u) << 16;
  return v.f;
}

// ---------------- fp32 -> bf16 convert (vectorized) ----------------
__global__ __launch_bounds__(256) void cvt_f32_bf16(const float* __restrict__ src,
                                                    u16* __restrict__ dst, int n4) {
  int i = blockIdx.x * 256 + threadIdx.x;
  if (i >= n4) return;
  float4 v = ((const float4*)src)[i];
  u16x4 o;
  o[0] = f2b(v.x); o[1] = f2b(v.y); o[2] = f2b(v.z); o[3] = f2b(v.w);
  ((u16x4*)dst)[i] = o;
}

// ---------------- RoPE cos/sin table: [2048][64] float2 ----------------
__global__ __launch_bounds__(256) void rope_table_k(float2* __restrict__ tbl) {
  int t = blockIdx.x * 256 + threadIdx.x;  // 131072 total
  int l = t >> 6, d = t & 63;
  float freq = exp2f(-0.20762050593045952f * (float)d);  // 10000^(-d/64)
  float a = (float)l * freq;
  float s, c;
  sincosf(a, &s, &c);
  tbl[t] = make_float2(c, s);
}

// ---------------- RoPE apply in-place on Q and K ([B,L,D] bf16) ----------------
// Q additionally scaled by qscale = hd^-0.5 * log2(e)  (attn works in exp2 domain)
__global__ __launch_bounds__(256) void rope_apply_k(u16* __restrict__ Q, u16* __restrict__ K,
                                                    const float2* __restrict__ tbl,
                                                    float qscale) {
  int t = blockIdx.x * 256 + threadIdx.x;  // 1,048,576 total
  int tensor = t >> 19;
  int idx = t & 524287;
  int g = idx & 7;           // d-group: d0 = g*8 in [0,64)
  int rest = idx >> 3;       // b*32768 + l*16 + h
  int h = rest & 15;
  int l = (rest >> 4) & 2047;
  int b = rest >> 15;
  u16* base = (tensor ? K : Q) + (((size_t)(b * 2048 + l)) << 11) + h * 128 + g * 8;
  float sc = tensor ? 1.0f : qscale;
  u16x8 v1 = *(const u16x8*)base;        // d..d+8
  u16x8 v2 = *(const u16x8*)(base + 64); // d+64..d+72
  const float2* cs = tbl + l * 64 + g * 8;
  u16x8 o1, o2;
#pragma unroll
  for (int j = 0; j < 8; ++j) {
    float a = b2f((u16)v1[j]), bb = b2f((u16)v2[j]);
    float c = cs[j].x, s = cs[j].y;
    o1[j] = f2b((a * c - bb * s) * sc);
    o2[j] = f2b((bb * c + a * s) * sc);
  }
  *(u16x8*)base = o1;
  *(u16x8*)(base + 64) = o2;
}

// ======== 256x256 8-phase GEMM (T2+T3+T4+T5), NT: C = A * B^T ========
// A: [M][2048] bf16, B: [N][2048] bf16 (rows = output cols), K = 2048.
// 512 threads = 8 waves (2M x 4N); per-wave C = rows {wm*64+mh*128+...},
// cols {wn*32+nh*128+...} so each quadrant's union over waves = one LDS
// half-tile [128][64] -> dead-region prefetch staging is race-free.
// LDS: 2 slots x 4 half-tiles (A0,A1,B0,B1) x [128][64] = 128 KiB.
// Swizzle (both sides, rule #21): chunk ^= row&7 -> read kgx = kg^(qr&7).
// Counted vmcnt: steady vmcnt(6) at phase 4 only; drain vmcnt(0) at t=30.
// MODE 0: fp32 C row-major [M][2048]. MODE 1: QKV epilogue by n-segment.
template <int MODE>
__global__ __launch_bounds__(512, 2) void gemm8(const u16* __restrict__ A,
                                                const u16* __restrict__ B,
                                                float* __restrict__ Cf,
                                                u16* __restrict__ Qo,
                                                u16* __restrict__ Ko,
                                                u16* __restrict__ Vo) {
  __shared__ u16 lds[2][4][8192];
  const int tid = threadIdx.x;
  const int lane = tid & 63;
  const int w = tid >> 6, wm = w >> 2, wn = w & 3;
  const int qr = lane & 15, kg = lane >> 4;
  const size_t m0 = (size_t)blockIdx.y * 256;
  const size_t n0 = (size_t)blockIdx.x * 256;
  const u16* Ab0 = A + m0 * 2048;
  const u16* Ab1 = A + (m0 + 128) * 2048;
  const u16* Bb0 = B + n0 * 2048;
  const u16* Bb1 = B + (n0 + 128) * 2048;

  // staging descriptors: LDS chunk i holds logical chunk i^((i>>3)&7 on col)
  const int i0 = tid, i1 = tid + 512;
  const size_t so0 = (size_t)(i0 >> 3) * 2048 + (((i0 & 7) ^ ((i0 >> 3) & 7)) << 3);
  const size_t so1 = (size_t)(i1 >> 3) * 2048 + (((i1 & 7) ^ ((i1 >> 3) & 7)) << 3);
  const int d0 = i0 * 8, d1 = i1 * 8;

#define STG(slot, half, bp, t)                                          \
  {                                                                     \
    GLOAD_LDS16((bp) + (size_t)(t) * 64 + so0, &lds[slot][half][d0]);   \
    GLOAD_LDS16((bp) + (size_t)(t) * 64 + so1, &lds[slot][half][d1]);   \
  }

  const int kgx = ((kg ^ (qr & 7)) << 4);          // swizzled chunk byte, kk=0
  const int abase = (wm * 64 + qr) * 128;          // bytes within A half-tile
  const int bbase = (wn * 32 + qr) * 128;          // bytes within B half-tile

  f32x4 acc[2][2][4][2] = {};
  s16x8 af[4][2], bf[2][2];

#define RD_A(mh)                                                                          \
  { _Pragma("unroll") for (int mi = 0; mi < 4; ++mi) {                                    \
      af[mi][0] = *(const s16x8*)((const char*)lds[cs][mh] + abase + mi * 2048 + kgx);    \
      af[mi][1] = *(const s16x8*)((const char*)lds[cs][mh] + abase + mi * 2048 + (kgx ^ 64)); } }
#define RD_B(nh)                                                                          \
  { _Pragma("unroll") for (int ni = 0; ni < 2; ++ni) {                                    \
      bf[ni][0] = *(const s16x8*)((const char*)lds[cs][2 + nh] + bbase + ni * 2048 + kgx); \
      bf[ni][1] = *(const s16x8*)((const char*)lds[cs][2 + nh] + bbase + ni * 2048 + (kgx ^ 64)); } }
#define MM(mh, nh)                                                                        \
  { _Pragma("unroll") for (int mi = 0; mi < 4; ++mi)                                      \
      _Pragma("unroll") for (int ni = 0; ni < 2; ++ni) {                                  \
        acc[mh][nh][mi][ni] = MFMA16(af[mi][0], bf[ni][0], acc[mh][nh][mi][ni]);          \
        acc[mh][nh][mi][ni] = MFMA16(af[mi][1], bf[ni][1], acc[mh][nh][mi][ni]); } }
#define OPENB  __builtin_amdgcn_s_barrier(); asm volatile("s_waitcnt lgkmcnt(0)" ::: "memory")
#define CLOSEB asm volatile("" ::: "memory"); __builtin_amdgcn_s_barrier()

  // prologue: tile0 all halves; tile1 A0,B1,A1 (B0(1) staged at t=0 phase1)
  STG(0, 0, Ab0, 0); STG(0, 1, Ab1, 0); STG(0, 2, Bb0, 0); STG(0, 3, Bb1, 0);
  STG(1, 0, Ab0, 1); STG(1, 3, Bb1, 1); STG(1, 1, Ab1, 1);
  asm volatile("s_waitcnt vmcnt(6)" ::: "memory");  // tile 0 fully landed
  __builtin_amdgcn_s_barrier();

  for (int t = 0; t < 32; ++t) {
    const int cs = t & 1, cn = cs ^ 1;
    // phase 1: quadrant (mh0, nh0); stage B0(t+1) into other slot (fully dead)
    RD_A(0); RD_B(0);
    if (t + 1 < 32) STG(cn, 2, Bb0, t + 1);
    OPENB;
    __builtin_amdgcn_s_setprio(1); MM(0, 0); __builtin_amdgcn_s_setprio(0);
    CLOSEB;
    // phase 2: quadrant (mh0, nh1); A-half0 dead after phase 1 -> stage A0(t+2)
    RD_B(1);
    if (t + 2 < 32) STG(cs, 0, Ab0, t + 2);
    OPENB;
    __builtin_amdgcn_s_setprio(1); MM(0, 1); __builtin_amdgcn_s_setprio(0);
    CLOSEB;
    // phase 3: quadrant (mh1, nh1); B-half1 dead after phase 2 -> stage B1(t+2)
    RD_A(1);
    if (t + 2 < 32) STG(cs, 3, Bb1, t + 2);
    OPENB;
    __builtin_amdgcn_s_setprio(1); MM(1, 1); __builtin_amdgcn_s_setprio(0);
    CLOSEB;
    // phase 4: quadrant (mh1, nh0); A-half1 dead after phase 3 -> stage A1(t+2)
    RD_B(0);
    if (t + 2 < 32) STG(cs, 1, Ab1, t + 2);
    OPENB;
    __builtin_amdgcn_s_setprio(1); MM(1, 0); __builtin_amdgcn_s_setprio(0);
    if (t < 30) { asm volatile("s_waitcnt vmcnt(6)" ::: "memory"); }  // 3 half-tiles in flight
    else        { asm volatile("s_waitcnt vmcnt(0)" ::: "memory"); }  // drain
    CLOSEB;
  }

  // epilogue
  const int seg = (MODE == 1) ? (int)(blockIdx.x >> 3) : 0;  // 2048-col segment
#pragma unroll
  for (int mh = 0; mh < 2; ++mh)
#pragma unroll
    for (int nh = 0; nh < 2; ++nh)
#pragma unroll
      for (int mi = 0; mi < 4; ++mi)
#pragma unroll
        for (int ni = 0; ni < 2; ++ni)
#pragma unroll
          for (int r = 0; r < 4; ++r) {
            size_t m = m0 + wm * 64 + mh * 128 + mi * 16 + kg * 4 + r;
            size_t n = n0 + wn * 32 + nh * 128 + ni * 16 + qr;
            float v = acc[mh][nh][mi][ni][r];
            if (MODE == 0) {
              Cf[m * 2048 + n] = v;
            } else {
              size_t n2 = n & 2047;
              if (seg == 0)      Qo[m * 2048 + n2] = f2b(v);
              else if (seg == 1) Ko[m * 2048 + n2] = f2b(v);
              else               Vo[((m >> 11) << 22) + (n2 << 11) + (m & 2047)] = f2b(v);
            }
          }
#undef STG
#undef RD_A
#undef RD_B
#undef MM
#undef OPENB
#undef CLOSEB
}

// ---------------- flash attention v3: swapped QK^T, in-register P ----------------
// Q,K: [B,L,D] bf16 (Q pre-scaled by hd^-0.5*log2e); V: Vt[b,h,d,l]; O: [B,L,D] bf16
__global__ __launch_bounds__(512, 4) void attn_k(const u16* __restrict__ Q,
                                                 const u16* __restrict__ K,
                                                 const u16* __restrict__ V,
                                                 u16* __restrict__ O) {
  __shared__ u16 sK[2][64 * 128];   // 2 x 16 KB
  __shared__ u16 sV[2][128 * 64];   // 2 x 16 KB
  const int tid = threadIdx.x;
  const int lane = tid & 63;
  const int w = tid >> 6;           // 0..7
  const int qr = lane & 15;
  const int kg = lane >> 4;
  const int bh = blockIdx.y;
  const size_t bbase = (size_t)(bh >> 4) * (2048 * 2048);
  const int hoff = (bh & 15) * 128;
  const int q0 = blockIdx.x * 128 + w * 16;

  const u16* Qrow = Q + bbase + (size_t)(q0 + qr) * 2048 + hoff;
  const u16* Kh = K + bbase + hoff;
  const u16* Vh = V + ((size_t)bh << 18);

  int kOff[2], vOff[2];
#pragma unroll
  for (int j = 0; j < 2; ++j) {
    int c = j * 512 + tid;
    int rk = c >> 4, sck = c & 15;
    kOff[j] = rk * 2048 + ((sck ^ (rk & 7)) << 3);
    int rv = c >> 3, scv = c & 7;
    vOff[j] = rv * 2048 + ((scv ^ (rv & 7)) << 3);
  }

#define STAGE_KV(bsel, kof)                                                    \
  {                                                                            \
    _Pragma("unroll") for (int j = 0; j < 2; ++j)                              \
        GLOAD_LDS16(Kh + (size_t)(kof) * 2048 + kOff[j],                       \
                    sK[bsel] + (j * 512 + tid) * 8);                           \
    _Pragma("unroll") for (int j = 0; j < 2; ++j)                              \
        GLOAD_LDS16(Vh + (kof) + vOff[j], sV[bsel] + (j * 512 + tid) * 8);     \
  }

  s16x8 aq[4];
#pragma unroll
  for (int c = 0; c < 4; ++c) aq[c] = *(const s16x8*)(Qrow + c * 32 + kg * 8);

  f32x4 o[8] = {};
  float mrow = -1e30f;
  float lrow = 0.f;
  float mprev[4] = {-1e30f, -1e30f, -1e30f, -1e30f};
  const int srcLo = qr + 32 * (kg & 1);
  const int srcHi = srcLo + 16;

  STAGE_KV(0, 0);
  int buf = 0;

  for (int k0 = 0; k0 < 2048; k0 += 64) {
    if (k0 + 64 < 2048) {
      STAGE_KV(buf ^ 1, k0 + 64);
      asm volatile("s_waitcnt vmcnt(4)" ::: "memory");
    } else {
      asm volatile("s_waitcnt vmcnt(0)" ::: "memory");
    }
    __builtin_amdgcn_s_barrier();
    const u16* sKb = sK[buf];
    const u16* sVb = sV[buf];

    f32x4 st[4];
#pragma unroll
    for (int kt = 0; kt < 4; ++kt) {
      int rn = kt * 16 + qr;
      f32x4 a = {0.f, 0.f, 0.f, 0.f};
#pragma unroll
      for (int c = 0; c < 4; ++c) {
        int cc = c * 4 + kg;
        s16x8 bk = *(const s16x8*)(sKb + rn * 128 + ((cc ^ (rn & 7)) << 3));
        a = MFMA16(bk, aq[c], a);
      }
      st[kt] = a;
    }

    float pm = fmaxf(fmaxf(fmaxf(st[0][0], st[0][1]), fmaxf(st[0][2], st[0][3])),
                     fmaxf(fmaxf(st[1][0], st[1][1]), fmaxf(st[1][2], st[1][3])));
    pm = fmaxf(pm,
               fmaxf(fmaxf(fmaxf(st[2][0], st[2][1]), fmaxf(st[2][2], st[2][3])),
                     fmaxf(fmaxf(st[3][0], st[3][1]), fmaxf(st[3][2], st[3][3]))));
    pm = fmaxf(pm, __shfl_xor(pm, 16, 64));
    pm = fmaxf(pm, __shfl_xor(pm, 32, 64));

    if (__any(pm > mrow + 8.f)) {
      float mnew = fmaxf(mrow, pm);
      lrow *= exp2f(mrow - mnew);
      mrow = mnew;
#pragma unroll
      for (int r = 0; r < 4; ++r) {
        float mnr = __shfl(mrow, kg * 4 + r, 64);
        float cfr = exp2f(mprev[r] - mnr);
        mprev[r] = mnr;
#pragma unroll
        for (int dt = 0; dt < 8; ++dt) o[dt][r] *= cfr;
      }
    }

    unsigned w2[8];
    float lsum = 0.f;
#pragma unroll
    for (int kt = 0; kt < 4; ++kt) {
      float p0 = exp2f(st[kt][0] - mrow), p1 = exp2f(st[kt][1] - mrow);
      float p2 = exp2f(st[kt][2] - mrow), p3 = exp2f(st[kt][3] - mrow);
      lsum += (p0 + p1) + (p2 + p3);
      asm("v_cvt_pk_bf16_f32 %0, %1, %2" : "=v"(w2[kt * 2]) : "v"(p0), "v"(p1));
      asm("v_cvt_pk_bf16_f32 %0, %1, %2" : "=v"(w2[kt * 2 + 1]) : "v"(p2), "v"(p3));
    }
    lrow += lsum;

    unsigned pw[8];
#pragma unroll
    for (int f = 0; f < 2; ++f) {
#pragma unroll
      for (int jj = 0; jj < 4; ++jj) {
        int src = (jj < 2) ? srcLo : srcHi;
        unsigned ra = (unsigned)__shfl((int)w2[4 * f + (jj & 1)], src, 64);
        unsigned rb = (unsigned)__shfl((int)w2[4 * f + 2 + (jj & 1)], src, 64);
        pw[f * 4 + jj] = (kg < 2) ? ra : rb;
      }
    }
    union { u32x4 u; s16x8 s; } ua, ub;
    ua.u = (u32x4){pw[0], pw[1], pw[2], pw[3]};
    ub.u = (u32x4){pw[4], pw[5], pw[6], pw[7]};

#pragma unroll
    for (int dt = 0; dt < 8; ++dt) {
      int n = dt * 16 + qr;
      s16x8 bv0 = *(const s16x8*)(sVb + n * 64 + ((kg ^ (n & 7)) << 3));
      s16x8 bv1 = *(const s16x8*)(sVb + n * 64 + (((4 + kg) ^ (n & 7)) << 3));
      o[dt] = MFMA16(ua.s, bv0, o[dt]);
      o[dt] = MFMA16(ub.s, bv1, o[dt]);
    }
    __builtin_amdgcn_s_barrier();
    buf ^= 1;
  }

  lrow += __shfl_xor(lrow, 16, 64);
  lrow += __shfl_xor(lrow, 32, 64);

  u16* Ob = O + bbase + hoff;
#pragma unroll
  for (int r = 0; r < 4; ++r) {
    float inv = 1.0f / __shfl(lrow, kg * 4 + r, 64);
    u16* orow = Ob + (size_t)(q0 + kg * 4 + r) * 2048;
#pragma unroll
    for (int dt = 0; dt < 8; ++dt) orow[dt * 16 + qr] = f2b(o[dt][r] * inv);
  }
#undef STAGE_KV
}

// ---------------- confidence head: logits = out . Wc; conf = sigmoid ----------------
__global__ __launch_bounds__(256) void conf_k(const float* __restrict__ out,
                                              const float* __restrict__ Wc,
                                              float* __restrict__ conf,
                                              float* __restrict__ logits) {
  int row = blockIdx.x * 4 + (threadIdx.x >> 6);  // 4096 rows
  int lane = threadIdx.x & 63;
  const float* r = out + (size_t)row * 2048;
  float sum = 0.f;
#pragma unroll
  for (int j = 0; j < 8; ++j) {
    int i = (j * 64 + lane) * 4;
    float4 a = *(const float4*)(r + i);
    float4 b = *(const float4*)(Wc + i);
    sum += a.x * b.x + a.y * b.y + a.z * b.z + a.w * b.w;
  }
#pragma unroll
  for (int off = 1; off < 64; off <<= 1) sum += __shfl_xor(sum, off, 64);
  if (lane == 0) {
    logits[row] = sum;
    conf[row] = 1.0f / (1.0f + __expf(-sum));
  }
}

extern "C" void kernel_launch(void* const* d_in, const int* in_sizes, int n_in,
                              void* d_out, int out_size, void* d_ws, size_t ws_size,
                              hipStream_t stream) {
  const float* x = (const float*)d_in[0];
  const float* Wq = (const float*)d_in[1];
  const float* Wk = (const float*)d_in[2];
  const float* Wv = (const float*)d_in[3];
  const float* Wo = (const float*)d_in[4];
  const float* Wc = (const float*)d_in[5];
  float* out = (float*)d_out;

  char* ws = (char*)d_ws;
  u16* xb    = (u16*)(ws + 0);          // 16 MB; attn output reuses it
  u16* Wqkvb = (u16*)(ws + 16777216);   // 24 MB [Wq;Wk;Wv]; later reused for Wo
  u16* Qb    = (u16*)(ws + 41943040);   // 16 MB
  u16* Kb    = (u16*)(ws + 58720256);   // 16 MB
  u16* Vt    = (u16*)(ws + 75497472);   // 16 MB
  float2* tbl = (float2*)(ws + 92274688);  // 1 MB

  cvt_f32_bf16<<<8192, 256, 0, stream>>>(x, xb, 2097152);
  cvt_f32_bf16<<<4096, 256, 0, stream>>>(Wq, Wqkvb, 1048576);
  cvt_f32_bf16<<<4096, 256, 0, stream>>>(Wk, Wqkvb + 4194304, 1048576);
  cvt_f32_bf16<<<4096, 256, 0, stream>>>(Wv, Wqkvb + 8388608, 1048576);
  rope_table_k<<<512, 256, 0, stream>>>(tbl);

  // fused QKV: M=4096, N=6144 (grid 24x16), epilogue splits Q/K/Vt
  gemm8<1><<<dim3(24, 16), 512, 0, stream>>>(xb, Wqkvb, nullptr, Qb, Kb, Vt);

  cvt_f32_bf16<<<4096, 256, 0, stream>>>(Wo, Wqkvb, 1048576);  // QKV GEMM retired

  // qscale = 128^-0.5 * log2(e): attention computes softmax in exp2 domain
  rope_apply_k<<<4096, 256, 0, stream>>>(Qb, Kb, tbl, 0.1275174093403682f);

  attn_k<<<dim3(16, 32), 512, 0, stream>>>(Qb, Kb, Vt, xb);  // xb now holds attn out

  // output projection: M=4096, N=2048 (grid 8x16), fp32 out
  gemm8<0><<<dim3(8, 16), 512, 0, stream>>>(xb, Wqkvb, out, nullptr, nullptr, nullptr);

  conf_k<<<1024, 256, 0, stream>>>(out, Wc, out + 8388608, out + 8392704);
}

// Round 10
// 458.422 us; speedup vs baseline: 1.7854x; 1.0571x over previous
//
#include <hip/hip_runtime.h>

typedef unsigned short u16;
typedef short s16x8 __attribute__((ext_vector_type(8)));
typedef u16 u16x8 __attribute__((ext_vector_type(8)));
typedef u16 u16x4 __attribute__((ext_vector_type(4)));
typedef float f32x4 __attribute__((ext_vector_type(4)));
typedef unsigned u32x4 __attribute__((ext_vector_type(4)));

#define MFMA16(A, B, C) __builtin_amdgcn_mfma_f32_16x16x32_bf16(A, B, C, 0, 0, 0)
#define GLOAD_LDS16(g, l) \
  __builtin_amdgcn_global_load_lds((const __attribute__((address_space(1))) void*)(g), \
                                   (__attribute__((address_space(3))) void*)(l), 16, 0, 0)

__device__ __forceinline__ u16 f2b(float f) {
  union { float f; unsigned u; } v; v.f = f;
  unsigned r = v.u + 0x7fffu + ((v.u >> 16) & 1u);
  return (u16)(r >> 16);
}
__device__ __forceinline__ float b2f(u16 u) {
  union { unsigned u; float f; } v; v.u = ((unsigned)u) << 16;
  return v.f;
}

// ---------------- fp32 -> bf16 convert (vectorized) ----------------
__global__ __launch_bounds__(256) void cvt_f32_bf16(const float* __restrict__ src,
                                                    u16* __restrict__ dst, int n4) {
  int i = blockIdx.x * 256 + threadIdx.x;
  if (i >= n4) return;
  float4 v = ((const float4*)src)[i];
  u16x4 o;
  o[0] = f2b(v.x); o[1] = f2b(v.y); o[2] = f2b(v.z); o[3] = f2b(v.w);
  ((u16x4*)dst)[i] = o;
}

// ---------------- RoPE cos/sin table: [2048][64] float2 ----------------
__global__ __launch_bounds__(256) void rope_table_k(float2* __restrict__ tbl) {
  int t = blockIdx.x * 256 + threadIdx.x;  // 131072 total
  int l = t >> 6, d = t & 63;
  float freq = exp2f(-0.20762050593045952f * (float)d);  // 10000^(-d/64)
  float a = (float)l * freq;
  float s, c;
  sincosf(a, &s, &c);
  tbl[t] = make_float2(c, s);
}

// ---------------- RoPE apply in-place on Q and K ([B,L,D] bf16) ----------------
// Q additionally scaled by qscale = hd^-0.5 * log2(e)  (attn works in exp2 domain)
__global__ __launch_bounds__(256) void rope_apply_k(u16* __restrict__ Q, u16* __restrict__ K,
                                                    const float2* __restrict__ tbl,
                                                    float qscale) {
  int t = blockIdx.x * 256 + threadIdx.x;  // 1,048,576 total
  int tensor = t >> 19;
  int idx = t & 524287;
  int g = idx & 7;           // d-group: d0 = g*8 in [0,64)
  int rest = idx >> 3;       // b*32768 + l*16 + h
  int h = rest & 15;
  int l = (rest >> 4) & 2047;
  int b = rest >> 15;
  u16* base = (tensor ? K : Q) + (((size_t)(b * 2048 + l)) << 11) + h * 128 + g * 8;
  float sc = tensor ? 1.0f : qscale;
  u16x8 v1 = *(const u16x8*)base;        // d..d+8
  u16x8 v2 = *(const u16x8*)(base + 64); // d+64..d+72
  const float2* cs = tbl + l * 64 + g * 8;
  u16x8 o1, o2;
#pragma unroll
  for (int j = 0; j < 8; ++j) {
    float a = b2f((u16)v1[j]), bb = b2f((u16)v2[j]);
    float c = cs[j].x, s = cs[j].y;
    o1[j] = f2b((a * c - bb * s) * sc);
    o2[j] = f2b((bb * c + a * s) * sc);
  }
  *(u16x8*)base = o1;
  *(u16x8*)(base + 64) = o2;
}

// ---------------- m97-structure NT GEMM (proven 2 blk/CU): C = A * B^T ----------
// MODE 0: fp32 row-major out; MODE 1: bf16 row-major out
template <int MODE>
__global__ __launch_bounds__(256, 2) void gemm_nt(const u16* __restrict__ A,
                                                  const u16* __restrict__ B,
                                                  float* __restrict__ Cf,
                                                  u16* __restrict__ Cb,
                                                  int M, int N, int K) {
  __shared__ u16 sA[128 * 64];
  __shared__ u16 sB[128 * 64];
  const int tid = threadIdx.x;
  const int lane = tid & 63;
  const int w = tid >> 6;
  const int wr = (w >> 1) * 64;
  const int wc = (w & 1) * 64;
  const int qr = lane & 15;
  const int kg = lane >> 4;
  const size_t m0 = (size_t)blockIdx.y * 128;
  const size_t n0 = (size_t)blockIdx.x * 128;

  f32x4 acc[4][4] = {};

  for (int k0 = 0; k0 < K; k0 += 64) {
#pragma unroll
    for (int j = 0; j < 4; ++j) {
      int i = j * 256 + tid;
      const u16* ga = A + (m0 + (i >> 3)) * (size_t)K + k0 + (i & 7) * 8;
      GLOAD_LDS16(ga, sA + i * 8);
    }
#pragma unroll
    for (int j = 0; j < 4; ++j) {
      int i = j * 256 + tid;
      const u16* gb = B + (n0 + (i >> 3)) * (size_t)K + k0 + (i & 7) * 8;
      GLOAD_LDS16(gb, sB + i * 8);
    }
    __syncthreads();
#pragma unroll
    for (int kk = 0; kk < 2; ++kk) {
      const int ko = kk * 32 + kg * 8;
      s16x8 af[4], bfr[4];
#pragma unroll
      for (int mi = 0; mi < 4; ++mi)
        af[mi] = *(const s16x8*)(sA + (wr + mi * 16 + qr) * 64 + ko);
#pragma unroll
      for (int ni = 0; ni < 4; ++ni)
        bfr[ni] = *(const s16x8*)(sB + (wc + ni * 16 + qr) * 64 + ko);
#pragma unroll
      for (int mi = 0; mi < 4; ++mi)
#pragma unroll
        for (int ni = 0; ni < 4; ++ni)
          acc[mi][ni] = MFMA16(af[mi], bfr[ni], acc[mi][ni]);
    }
    __syncthreads();
  }

#pragma unroll
  for (int mi = 0; mi < 4; ++mi) {
#pragma unroll
    for (int ni = 0; ni < 4; ++ni) {
#pragma unroll
      for (int r = 0; r < 4; ++r) {
        size_t m = m0 + wr + mi * 16 + kg * 4 + r;
        size_t n = n0 + wc + ni * 16 + qr;
        float v = acc[mi][ni][r];
        if (MODE == 0) Cf[m * (size_t)N + n] = v;
        else           Cb[m * (size_t)N + n] = f2b(v);
      }
    }
  }
}

// ======== 256x256 8-phase GEMM (T2+T3+T4+T5), NT: C = A * B^T ========
// QKV only: A [4096][2048], B [6144][2048]; epilogue row-major by n-segment
// (Q, K, Vrow). All stores coalesced; V transposed later by transpose_v.
__global__ __launch_bounds__(512, 2) void gemm8(const u16* __restrict__ A,
                                                const u16* __restrict__ B,
                                                u16* __restrict__ Qo,
                                                u16* __restrict__ Ko,
                                                u16* __restrict__ Vo) {
  __shared__ u16 lds[2][4][8192];
  const int tid = threadIdx.x;
  const int lane = tid & 63;
  const int w = tid >> 6, wm = w >> 2, wn = w & 3;
  const int qr = lane & 15, kg = lane >> 4;
  const size_t m0 = (size_t)blockIdx.y * 256;
  const size_t n0 = (size_t)blockIdx.x * 256;
  const u16* Ab0 = A + m0 * 2048;
  const u16* Ab1 = A + (m0 + 128) * 2048;
  const u16* Bb0 = B + n0 * 2048;
  const u16* Bb1 = B + (n0 + 128) * 2048;

  const int i0 = tid, i1 = tid + 512;
  const size_t so0 = (size_t)(i0 >> 3) * 2048 + (((i0 & 7) ^ ((i0 >> 3) & 7)) << 3);
  const size_t so1 = (size_t)(i1 >> 3) * 2048 + (((i1 & 7) ^ ((i1 >> 3) & 7)) << 3);
  const int d0 = i0 * 8, d1 = i1 * 8;

#define STG(slot, half, bp, t)                                          \
  {                                                                     \
    GLOAD_LDS16((bp) + (size_t)(t) * 64 + so0, &lds[slot][half][d0]);   \
    GLOAD_LDS16((bp) + (size_t)(t) * 64 + so1, &lds[slot][half][d1]);   \
  }

  const int kgx = ((kg ^ (qr & 7)) << 4);
  const int abase = (wm * 64 + qr) * 128;
  const int bbase = (wn * 32 + qr) * 128;

  f32x4 acc[2][2][4][2] = {};
  s16x8 af[4][2], bf[2][2];

#define RD_A(mh)                                                                          \
  { _Pragma("unroll") for (int mi = 0; mi < 4; ++mi) {                                    \
      af[mi][0] = *(const s16x8*)((const char*)lds[cs][mh] + abase + mi * 2048 + kgx);    \
      af[mi][1] = *(const s16x8*)((const char*)lds[cs][mh] + abase + mi * 2048 + (kgx ^ 64)); } }
#define RD_B(nh)                                                                          \
  { _Pragma("unroll") for (int ni = 0; ni < 2; ++ni) {                                    \
      bf[ni][0] = *(const s16x8*)((const char*)lds[cs][2 + nh] + bbase + ni * 2048 + kgx); \
      bf[ni][1] = *(const s16x8*)((const char*)lds[cs][2 + nh] + bbase + ni * 2048 + (kgx ^ 64)); } }
#define MM(mh, nh)                                                                        \
  { _Pragma("unroll") for (int mi = 0; mi < 4; ++mi)                                      \
      _Pragma("unroll") for (int ni = 0; ni < 2; ++ni) {                                  \
        acc[mh][nh][mi][ni] = MFMA16(af[mi][0], bf[ni][0], acc[mh][nh][mi][ni]);          \
        acc[mh][nh][mi][ni] = MFMA16(af[mi][1], bf[ni][1], acc[mh][nh][mi][ni]); } }
#define OPENB  __builtin_amdgcn_s_barrier(); asm volatile("s_waitcnt lgkmcnt(0)" ::: "memory")
#define CLOSEB asm volatile("" ::: "memory"); __builtin_amdgcn_s_barrier()

  STG(0, 0, Ab0, 0); STG(0, 1, Ab1, 0); STG(0, 2, Bb0, 0); STG(0, 3, Bb1, 0);
  STG(1, 0, Ab0, 1); STG(1, 3, Bb1, 1); STG(1, 1, Ab1, 1);
  asm volatile("s_waitcnt vmcnt(6)" ::: "memory");
  __builtin_amdgcn_s_barrier();

  for (int t = 0; t < 32; ++t) {
    const int cs = t & 1, cn = cs ^ 1;
    RD_A(0); RD_B(0);
    if (t + 1 < 32) STG(cn, 2, Bb0, t + 1);
    OPENB;
    __builtin_amdgcn_s_setprio(1); MM(0, 0); __builtin_amdgcn_s_setprio(0);
    CLOSEB;
    RD_B(1);
    if (t + 2 < 32) STG(cs, 0, Ab0, t + 2);
    OPENB;
    __builtin_amdgcn_s_setprio(1); MM(0, 1); __builtin_amdgcn_s_setprio(0);
    CLOSEB;
    RD_A(1);
    if (t + 2 < 32) STG(cs, 3, Bb1, t + 2);
    OPENB;
    __builtin_amdgcn_s_setprio(1); MM(1, 1); __builtin_amdgcn_s_setprio(0);
    CLOSEB;
    RD_B(0);
    if (t + 2 < 32) STG(cs, 1, Ab1, t + 2);
    OPENB;
    __builtin_amdgcn_s_setprio(1); MM(1, 0); __builtin_amdgcn_s_setprio(0);
    if (t < 30) { asm volatile("s_waitcnt vmcnt(6)" ::: "memory"); }
    else        { asm volatile("s_waitcnt vmcnt(0)" ::: "memory"); }
    CLOSEB;
  }

  const int seg = (int)(blockIdx.x >> 3);  // 2048-col segment: 0=Q 1=K 2=V
  u16* dst = (seg == 0) ? Qo : (seg == 1) ? Ko : Vo;
#pragma unroll
  for (int mh = 0; mh < 2; ++mh)
#pragma unroll
    for (int nh = 0; nh < 2; ++nh)
#pragma unroll
      for (int mi = 0; mi < 4; ++mi)
#pragma unroll
        for (int ni = 0; ni < 2; ++ni)
#pragma unroll
          for (int r = 0; r < 4; ++r) {
            size_t m = m0 + wm * 64 + mh * 128 + mi * 16 + kg * 4 + r;
            size_t n = n0 + wn * 32 + nh * 128 + ni * 16 + qr;
            dst[m * 2048 + (n & 2047)] = f2b(acc[mh][nh][mi][ni][r]);
          }
#undef STG
#undef RD_A
#undef RD_B
#undef MM
#undef OPENB
#undef CLOSEB
}

// ---------------- V transpose: Vrow [B,L,16,128] -> Vt [bh, d, l] ----------------
// 64x64 LDS tiles, padded to 65 (2-way max on read). Coalesced 32B both sides.
__global__ __launch_bounds__(256) void transpose_v(const u16* __restrict__ Vr,
                                                   u16* __restrict__ Vt) {
  __shared__ u16 tile[64][65];
  const int bh = blockIdx.y;                 // 0..31
  const int b = bh >> 4, h = bh & 15;
  const int l0 = (blockIdx.x & 31) * 64;     // 32 l-tiles
  const int d0 = (blockIdx.x >> 5) * 64;     // 2 d-tiles
  const int t = threadIdx.x;
  const int r = t >> 2, cq = (t & 3) * 16;
  const u16* src = Vr + ((size_t)(b * 2048 + l0 + r) << 11) + h * 128 + d0 + cq;
  u16x8 v0 = *(const u16x8*)src;
  u16x8 v1 = *(const u16x8*)(src + 8);
#pragma unroll
  for (int j = 0; j < 8; ++j) { tile[r][cq + j] = v0[j]; tile[r][cq + 8 + j] = v1[j]; }
  __syncthreads();
  const int dd = t >> 2, lq = (t & 3) * 16;
  u16x8 o0, o1;
#pragma unroll
  for (int j = 0; j < 8; ++j) { o0[j] = tile[lq + j][dd]; o1[j] = tile[lq + 8 + j][dd]; }
  u16* dst = Vt + ((size_t)bh << 18) + ((size_t)(d0 + dd) << 11) + l0 + lq;
  *(u16x8*)dst = o0;
  *(u16x8*)(dst + 8) = o1;
}

// ---------------- flash attention v3: swapped QK^T, in-register P ----------------
__global__ __launch_bounds__(512, 4) void attn_k(const u16* __restrict__ Q,
                                                 const u16* __restrict__ K,
                                                 const u16* __restrict__ V,
                                                 u16* __restrict__ O) {
  __shared__ u16 sK[2][64 * 128];
  __shared__ u16 sV[2][128 * 64];
  const int tid = threadIdx.x;
  const int lane = tid & 63;
  const int w = tid >> 6;
  const int qr = lane & 15;
  const int kg = lane >> 4;
  const int bh = blockIdx.y;
  const size_t bbase = (size_t)(bh >> 4) * (2048 * 2048);
  const int hoff = (bh & 15) * 128;
  const int q0 = blockIdx.x * 128 + w * 16;

  const u16* Qrow = Q + bbase + (size_t)(q0 + qr) * 2048 + hoff;
  const u16* Kh = K + bbase + hoff;
  const u16* Vh = V + ((size_t)bh << 18);

  int kOff[2], vOff[2];
#pragma unroll
  for (int j = 0; j < 2; ++j) {
    int c = j * 512 + tid;
    int rk = c >> 4, sck = c & 15;
    kOff[j] = rk * 2048 + ((sck ^ (rk & 7)) << 3);
    int rv = c >> 3, scv = c & 7;
    vOff[j] = rv * 2048 + ((scv ^ (rv & 7)) << 3);
  }

#define STAGE_KV(bsel, kof)                                                    \
  {                                                                            \
    _Pragma("unroll") for (int j = 0; j < 2; ++j)                              \
        GLOAD_LDS16(Kh + (size_t)(kof) * 2048 + kOff[j],                       \
                    sK[bsel] + (j * 512 + tid) * 8);                           \
    _Pragma("unroll") for (int j = 0; j < 2; ++j)                              \
        GLOAD_LDS16(Vh + (kof) + vOff[j], sV[bsel] + (j * 512 + tid) * 8);     \
  }

  s16x8 aq[4];
#pragma unroll
  for (int c = 0; c < 4; ++c) aq[c] = *(const s16x8*)(Qrow + c * 32 + kg * 8);

  f32x4 o[8] = {};
  float mrow = -1e30f;
  float lrow = 0.f;
  float mprev[4] = {-1e30f, -1e30f, -1e30f, -1e30f};
  const int srcLo = qr + 32 * (kg & 1);
  const int srcHi = srcLo + 16;

  STAGE_KV(0, 0);
  int buf = 0;

  for (int k0 = 0; k0 < 2048; k0 += 64) {
    if (k0 + 64 < 2048) {
      STAGE_KV(buf ^ 1, k0 + 64);
      asm volatile("s_waitcnt vmcnt(4)" ::: "memory");
    } else {
      asm volatile("s_waitcnt vmcnt(0)" ::: "memory");
    }
    __builtin_amdgcn_s_barrier();
    const u16* sKb = sK[buf];
    const u16* sVb = sV[buf];

    f32x4 st[4];
#pragma unroll
    for (int kt = 0; kt < 4; ++kt) {
      int rn = kt * 16 + qr;
      f32x4 a = {0.f, 0.f, 0.f, 0.f};
#pragma unroll
      for (int c = 0; c < 4; ++c) {
        int cc = c * 4 + kg;
        s16x8 bk = *(const s16x8*)(sKb + rn * 128 + ((cc ^ (rn & 7)) << 3));
        a = MFMA16(bk, aq[c], a);
      }
      st[kt] = a;
    }

    float pm = fmaxf(fmaxf(fmaxf(st[0][0], st[0][1]), fmaxf(st[0][2], st[0][3])),
                     fmaxf(fmaxf(st[1][0], st[1][1]), fmaxf(st[1][2], st[1][3])));
    pm = fmaxf(pm,
               fmaxf(fmaxf(fmaxf(st[2][0], st[2][1]), fmaxf(st[2][2], st[2][3])),
                     fmaxf(fmaxf(st[3][0], st[3][1]), fmaxf(st[3][2], st[3][3]))));
    pm = fmaxf(pm, __shfl_xor(pm, 16, 64));
    pm = fmaxf(pm, __shfl_xor(pm, 32, 64));

    if (__any(pm > mrow + 8.f)) {
      float mnew = fmaxf(mrow, pm);
      lrow *= exp2f(mrow - mnew);
      mrow = mnew;
#pragma unroll
      for (int r = 0; r < 4; ++r) {
        float mnr = __shfl(mrow, kg * 4 + r, 64);
        float cfr = exp2f(mprev[r] - mnr);
        mprev[r] = mnr;
#pragma unroll
        for (int dt = 0; dt < 8; ++dt) o[dt][r] *= cfr;
      }
    }

    unsigned w2[8];
    float lsum = 0.f;
#pragma unroll
    for (int kt = 0; kt < 4; ++kt) {
      float p0 = exp2f(st[kt][0] - mrow), p1 = exp2f(st[kt][1] - mrow);
      float p2 = exp2f(st[kt][2] - mrow), p3 = exp2f(st[kt][3] - mrow);
      lsum += (p0 + p1) + (p2 + p3);
      asm("v_cvt_pk_bf16_f32 %0, %1, %2" : "=v"(w2[kt * 2]) : "v"(p0), "v"(p1));
      asm("v_cvt_pk_bf16_f32 %0, %1, %2" : "=v"(w2[kt * 2 + 1]) : "v"(p2), "v"(p3));
    }
    lrow += lsum;

    unsigned pw[8];
#pragma unroll
    for (int f = 0; f < 2; ++f) {
#pragma unroll
      for (int jj = 0; jj < 4; ++jj) {
        int src = (jj < 2) ? srcLo : srcHi;
        unsigned ra = (unsigned)__shfl((int)w2[4 * f + (jj & 1)], src, 64);
        unsigned rb = (unsigned)__shfl((int)w2[4 * f + 2 + (jj & 1)], src, 64);
        pw[f * 4 + jj] = (kg < 2) ? ra : rb;
      }
    }
    union { u32x4 u; s16x8 s; } ua, ub;
    ua.u = (u32x4){pw[0], pw[1], pw[2], pw[3]};
    ub.u = (u32x4){pw[4], pw[5], pw[6], pw[7]};

#pragma unroll
    for (int dt = 0; dt < 8; ++dt) {
      int n = dt * 16 + qr;
      s16x8 bv0 = *(const s16x8*)(sVb + n * 64 + ((kg ^ (n & 7)) << 3));
      s16x8 bv1 = *(const s16x8*)(sVb + n * 64 + (((4 + kg) ^ (n & 7)) << 3));
      o[dt] = MFMA16(ua.s, bv0, o[dt]);
      o[dt] = MFMA16(ub.s, bv1, o[dt]);
    }
    __builtin_amdgcn_s_barrier();
    buf ^= 1;
  }

  lrow += __shfl_xor(lrow, 16, 64);
  lrow += __shfl_xor(lrow, 32, 64);

  u16* Ob = O + bbase + hoff;
#pragma unroll
  for (int r = 0; r < 4; ++r) {
    float inv = 1.0f / __shfl(lrow, kg * 4 + r, 64);
    u16* orow = Ob + (size_t)(q0 + kg * 4 + r) * 2048;
#pragma unroll
    for (int dt = 0; dt < 8; ++dt) orow[dt * 16 + qr] = f2b(o[dt][r] * inv);
  }
#undef STAGE_KV
}

// ---------------- confidence head: logits = out . Wc; conf = sigmoid ----------------
__global__ __launch_bounds__(256) void conf_k(const float* __restrict__ out,
                                              const float* __restrict__ Wc,
                                              float* __restrict__ conf,
                                              float* __restrict__ logits) {
  int row = blockIdx.x * 4 + (threadIdx.x >> 6);  // 4096 rows
  int lane = threadIdx.x & 63;
  const float* r = out + (size_t)row * 2048;
  float sum = 0.f;
#pragma unroll
  for (int j = 0; j < 8; ++j) {
    int i = (j * 64 + lane) * 4;
    float4 a = *(const float4*)(r + i);
    float4 b = *(const float4*)(Wc + i);
    sum += a.x * b.x + a.y * b.y + a.z * b.z + a.w * b.w;
  }
#pragma unroll
  for (int off = 1; off < 64; off <<= 1) sum += __shfl_xor(sum, off, 64);
  if (lane == 0) {
    logits[row] = sum;
    conf[row] = 1.0f / (1.0f + __expf(-sum));
  }
}

extern "C" void kernel_launch(void* const* d_in, const int* in_sizes, int n_in,
                              void* d_out, int out_size, void* d_ws, size_t ws_size,
                              hipStream_t stream) {
  const float* x = (const float*)d_in[0];
  const float* Wq = (const float*)d_in[1];
  const float* Wk = (const float*)d_in[2];
  const float* Wv = (const float*)d_in[3];
  const float* Wo = (const float*)d_in[4];
  const float* Wc = (const float*)d_in[5];
  float* out = (float*)d_out;

  char* ws = (char*)d_ws;
  u16* xb    = (u16*)(ws + 0);          // 16 MB; attn output reuses it
  u16* Wqkvb = (u16*)(ws + 16777216);   // 24 MB [Wq;Wk;Wv] during QKV GEMM
  u16* Wob   = (u16*)(ws + 16777216);   // 8 MB, overwrites Wq slot after QKV
  u16* Vt    = (u16*)(ws + 25165824);   // 16 MB, overwrites Wk/Wv slots after QKV
  u16* Qb    = (u16*)(ws + 41943040);   // 16 MB
  u16* Kb    = (u16*)(ws + 58720256);   // 16 MB
  u16* Vrow  = (u16*)(ws + 75497472);   // 16 MB (row-major V from QKV GEMM)
  float2* tbl = (float2*)(ws + 92274688);  // 1 MB

  cvt_f32_bf16<<<8192, 256, 0, stream>>>(x, xb, 2097152);
  cvt_f32_bf16<<<4096, 256, 0, stream>>>(Wq, Wqkvb, 1048576);
  cvt_f32_bf16<<<4096, 256, 0, stream>>>(Wk, Wqkvb + 4194304, 1048576);
  cvt_f32_bf16<<<4096, 256, 0, stream>>>(Wv, Wqkvb + 8388608, 1048576);
  rope_table_k<<<512, 256, 0, stream>>>(tbl);

  // fused QKV: M=4096, N=6144 (grid 24x16), all outputs row-major
  gemm8<<<dim3(24, 16), 512, 0, stream>>>(xb, Wqkvb, Qb, Kb, Vrow);

  // V transpose (QKV retired; Wk/Wv region now free)
  transpose_v<<<dim3(64, 32), 256, 0, stream>>>(Vrow, Vt);

  cvt_f32_bf16<<<4096, 256, 0, stream>>>(Wo, Wob, 1048576);

  // qscale = 128^-0.5 * log2(e): attention computes softmax in exp2 domain
  rope_apply_k<<<4096, 256, 0, stream>>>(Qb, Kb, tbl, 0.1275174093403682f);

  attn_k<<<dim3(16, 32), 512, 0, stream>>>(Qb, Kb, Vt, xb);  // xb now holds attn out

  // output projection: proven m97 structure (512 blocks, 2/CU)
  gemm_nt<0><<<dim3(16, 32), 256, 0, stream>>>(xb, Wob, out, nullptr, 4096, 2048, 2048);

  conf_k<<<1024, 256, 0, stream>>>(out, Wc, out + 8388608, out + 8392704);
}

// Round 11
// 445.943 us; speedup vs baseline: 1.8354x; 1.0280x over previous
//
#include <hip/hip_runtime.h>

typedef unsigned short u16;
typedef short s16x8 __attribute__((ext_vector_type(8)));
typedef u16 u16x8 __attribute__((ext_vector_type(8)));
typedef u16 u16x4 __attribute__((ext_vector_type(4)));
typedef float f32x4 __attribute__((ext_vector_type(4)));
typedef unsigned u32x4 __attribute__((ext_vector_type(4)));

#define MFMA16(A, B, C) __builtin_amdgcn_mfma_f32_16x16x32_bf16(A, B, C, 0, 0, 0)
#define GLOAD_LDS16(g, l) \
  __builtin_amdgcn_global_load_lds((const __attribute__((address_space(1))) void*)(g), \
                                   (__attribute__((address_space(3))) void*)(l), 16, 0, 0)

__device__ __forceinline__ u16 f2b(float f) {
  union { float f; unsigned u; } v; v.f = f;
  unsigned r = v.u + 0x7fffu + ((v.u >> 16) & 1u);
  return (u16)(r >> 16);
}
__device__ __forceinline__ float b2f(u16 u) {
  union { unsigned u; float f; } v; v.u = ((unsigned)u) << 16;
  return v.f;
}

// ---------------- fp32 -> bf16 convert (vectorized) ----------------
__global__ __launch_bounds__(256) void cvt_f32_bf16(const float* __restrict__ src,
                                                    u16* __restrict__ dst, int n4) {
  int i = blockIdx.x * 256 + threadIdx.x;
  if (i >= n4) return;
  float4 v = ((const float4*)src)[i];
  u16x4 o;
  o[0] = f2b(v.x); o[1] = f2b(v.y); o[2] = f2b(v.z); o[3] = f2b(v.w);
  ((u16x4*)dst)[i] = o;
}

// ---------------- fused Wq/Wk/Wv convert into one [3*2048][2048] buffer -----
__global__ __launch_bounds__(256) void cvt_w3(const float* __restrict__ Wq,
                                              const float* __restrict__ Wk,
                                              const float* __restrict__ Wv,
                                              u16* __restrict__ dst) {
  int t = blockIdx.x * 256 + threadIdx.x;   // 3,145,728 float4s
  int sel = t >> 20, idx = t & 1048575;
  const float* src = (sel == 0) ? Wq : (sel == 1) ? Wk : Wv;
  float4 v = ((const float4*)src)[idx];
  u16x4 o;
  o[0] = f2b(v.x); o[1] = f2b(v.y); o[2] = f2b(v.z); o[3] = f2b(v.w);
  ((u16x4*)(dst + (size_t)sel * 4194304))[idx] = o;
}

// ---------------- RoPE cos/sin table: [2048][64] float2 ----------------
__global__ __launch_bounds__(256) void rope_table_k(float2* __restrict__ tbl) {
  int t = blockIdx.x * 256 + threadIdx.x;  // 131072 total
  int l = t >> 6, d = t & 63;
  float freq = exp2f(-0.20762050593045952f * (float)d);  // 10000^(-d/64)
  float a = (float)l * freq;
  float s, c;
  sincosf(a, &s, &c);
  tbl[t] = make_float2(c, s);
}

// ---------------- RoPE apply in-place on Q and K ([B,L,D] bf16) ----------------
// Q additionally scaled by qscale = hd^-0.5 * log2(e)  (attn works in exp2 domain)
__global__ __launch_bounds__(256) void rope_apply_k(u16* __restrict__ Q, u16* __restrict__ K,
                                                    const float2* __restrict__ tbl,
                                                    float qscale) {
  int t = blockIdx.x * 256 + threadIdx.x;  // 1,048,576 total
  int tensor = t >> 19;
  int idx = t & 524287;
  int g = idx & 7;           // d-group: d0 = g*8 in [0,64)
  int rest = idx >> 3;       // b*32768 + l*16 + h
  int h = rest & 15;
  int l = (rest >> 4) & 2047;
  int b = rest >> 15;
  u16* base = (tensor ? K : Q) + (((size_t)(b * 2048 + l)) << 11) + h * 128 + g * 8;
  float sc = tensor ? 1.0f : qscale;
  u16x8 v1 = *(const u16x8*)base;        // d..d+8
  u16x8 v2 = *(const u16x8*)(base + 64); // d+64..d+72
  const float2* cs = tbl + l * 64 + g * 8;
  u16x8 o1, o2;
#pragma unroll
  for (int j = 0; j < 8; ++j) {
    float a = b2f((u16)v1[j]), bb = b2f((u16)v2[j]);
    float c = cs[j].x, s = cs[j].y;
    o1[j] = f2b((a * c - bb * s) * sc);
    o2[j] = f2b((bb * c + a * s) * sc);
  }
  *(u16x8*)base = o1;
  *(u16x8*)(base + 64) = o2;
}

// ======== 128x256 8-phase NT GEMM (T2+T4+T5): C = A * B^T ========
// A [M][2048], B [N][2048], K=2048. 8 waves, each owns a 64x64 output tile
// (wm in 0..1 rows, wn in 0..3 cols); waves wn<2 read B-half0, wn>=2 B-half1.
// LDS [2 slots][A,B0,B1][128x64 bf16] = 96 KB -> 1 blk/CU, exact grid rounds:
// QKV 24x32=768 (3 rounds), Wo 8x32=256 (1 round).
// 2 phases per K-step: ph1 {RD_B all + RD_A(mi01) | STG t+1 | bar+lgkm | 16 MFMA | bar}
//                      ph2 {RD_A(mi23) | bar+lgkm | 16 MFMA | vmcnt(0) | bar}
// Staging of t+1 issued in ph1 -> ~2 MFMA phases cover the load latency; single
// counted drain per K-step. Swizzle: both-sides chunk^=row&7 (0-conflict proven).
// MODE 0: fp32 C row-major [M][2048]; MODE 1: QKV epilogue by n-segment.
template <int MODE>
__global__ __launch_bounds__(512, 2) void gemm8h(const u16* __restrict__ A,
                                                 const u16* __restrict__ B,
                                                 float* __restrict__ Cf,
                                                 u16* __restrict__ Qo,
                                                 u16* __restrict__ Ko,
                                                 u16* __restrict__ Vo) {
  __shared__ u16 lds[2][3][8192];   // [slot][0=A,1=B0,2=B1][128*64]
  const int tid = threadIdx.x;
  const int lane = tid & 63;
  const int w = tid >> 6, wm = w >> 2, wn = w & 3;
  const int qr = lane & 15, kg = lane >> 4;
  const size_t m0 = (size_t)blockIdx.y * 128;
  const size_t n0 = (size_t)blockIdx.x * 256;
  const u16* Ab  = A + m0 * 2048;
  const u16* Bb0 = B + n0 * 2048;
  const u16* Bb1 = B + (n0 + 128) * 2048;

  // staging: LDS chunk i=(r,c) holds global col-chunk c^(r&7) of row r
  const int i0 = tid, i1 = tid + 512;
  const size_t so0 = (size_t)(i0 >> 3) * 2048 + (((i0 & 7) ^ ((i0 >> 3) & 7)) << 3);
  const size_t so1 = (size_t)(i1 >> 3) * 2048 + (((i1 & 7) ^ ((i1 >> 3) & 7)) << 3);
  const int d0 = i0 * 8, d1 = i1 * 8;

#define STG(slot, half, bp, t)                                          \
  {                                                                     \
    GLOAD_LDS16((bp) + (size_t)(t) * 64 + so0, &lds[slot][half][d0]);   \
    GLOAD_LDS16((bp) + (size_t)(t) * 64 + so1, &lds[slot][half][d1]);   \
  }

  const int kgx = ((kg ^ (qr & 7)) << 4);            // kk=0 swizzled chunk byte
  const int abase = (wm * 64 + qr) * 128;            // bytes in A half-tile
  const int hb = 1 + (wn >> 1);                      // B half for this wave
  const int bbase = ((wn & 1) * 64 + qr) * 128;      // bytes in B half-tile

  f32x4 acc[4][4] = {};
  s16x8 af[2][2], bf[4][2];

#define RD_A(mb)                                                                           \
  { _Pragma("unroll") for (int j = 0; j < 2; ++j) {                                        \
      af[j][0] = *(const s16x8*)((const char*)lds[cs][0] + abase + ((mb) + j) * 2048 + kgx); \
      af[j][1] = *(const s16x8*)((const char*)lds[cs][0] + abase + ((mb) + j) * 2048 + (kgx ^ 64)); } }
#define RD_B_ALL                                                                           \
  { _Pragma("unroll") for (int ni = 0; ni < 4; ++ni) {                                     \
      bf[ni][0] = *(const s16x8*)((const char*)lds[cs][hb] + bbase + ni * 2048 + kgx);     \
      bf[ni][1] = *(const s16x8*)((const char*)lds[cs][hb] + bbase + ni * 2048 + (kgx ^ 64)); } }
#define MM(mb)                                                                             \
  { _Pragma("unroll") for (int j = 0; j < 2; ++j)                                          \
      _Pragma("unroll") for (int ni = 0; ni < 4; ++ni) {                                   \
        acc[(mb) + j][ni] = MFMA16(af[j][0], bf[ni][0], acc[(mb) + j][ni]);                \
        acc[(mb) + j][ni] = MFMA16(af[j][1], bf[ni][1], acc[(mb) + j][ni]); } }
#define OPENB                                                   \
  __builtin_amdgcn_s_barrier();                                 \
  asm volatile("s_waitcnt lgkmcnt(0)" ::: "memory");            \
  __builtin_amdgcn_sched_barrier(0)
#define CLOSEB asm volatile("" ::: "memory"); __builtin_amdgcn_s_barrier()

  // prologue: tile 0 into slot 0, full drain
  STG(0, 0, Ab, 0); STG(0, 1, Bb0, 0); STG(0, 2, Bb1, 0);
  asm volatile("s_waitcnt vmcnt(0)" ::: "memory");
  __builtin_amdgcn_s_barrier();

  for (int t = 0; t < 32; ++t) {
    const int cs = t & 1, cn = cs ^ 1;
    // phase 1
    RD_B_ALL; RD_A(0);
    if (t + 1 < 32) { STG(cn, 0, Ab, t + 1); STG(cn, 1, Bb0, t + 1); STG(cn, 2, Bb1, t + 1); }
    OPENB;
    __builtin_amdgcn_s_setprio(1); MM(0); __builtin_amdgcn_s_setprio(0);
    CLOSEB;
    // phase 2
    RD_A(2);
    OPENB;
    __builtin_amdgcn_s_setprio(1); MM(2); __builtin_amdgcn_s_setprio(0);
    asm volatile("s_waitcnt vmcnt(0)" ::: "memory");  // t+1's 6 loads landed
    CLOSEB;
  }

  const int seg = (MODE == 1) ? (int)(blockIdx.x >> 3) : 0;  // 0=Q 1=K 2=V
  u16* dst = (MODE == 1) ? ((seg == 0) ? Qo : (seg == 1) ? Ko : Vo) : nullptr;
#pragma unroll
  for (int mi = 0; mi < 4; ++mi)
#pragma unroll
    for (int ni = 0; ni < 4; ++ni)
#pragma unroll
      for (int r = 0; r < 4; ++r) {
        size_t m = m0 + wm * 64 + mi * 16 + kg * 4 + r;
        size_t n = n0 + wn * 64 + ni * 16 + qr;
        float v = acc[mi][ni][r];
        if (MODE == 0) Cf[m * 2048 + n] = v;
        else           dst[m * 2048 + (n & 2047)] = f2b(v);
      }
#undef STG
#undef RD_A
#undef RD_B_ALL
#undef MM
#undef OPENB
#undef CLOSEB
}

// ---------------- V transpose: Vrow [B,L,16,128] -> Vt [bh, d, l] ----------------
__global__ __launch_bounds__(256) void transpose_v(const u16* __restrict__ Vr,
                                                   u16* __restrict__ Vt) {
  __shared__ u16 tile[64][65];
  const int bh = blockIdx.y;                 // 0..31
  const int b = bh >> 4, h = bh & 15;
  const int l0 = (blockIdx.x & 31) * 64;     // 32 l-tiles
  const int d0 = (blockIdx.x >> 5) * 64;     // 2 d-tiles
  const int t = threadIdx.x;
  const int r = t >> 2, cq = (t & 3) * 16;
  const u16* src = Vr + ((size_t)(b * 2048 + l0 + r) << 11) + h * 128 + d0 + cq;
  u16x8 v0 = *(const u16x8*)src;
  u16x8 v1 = *(const u16x8*)(src + 8);
#pragma unroll
  for (int j = 0; j < 8; ++j) { tile[r][cq + j] = v0[j]; tile[r][cq + 8 + j] = v1[j]; }
  __syncthreads();
  const int dd = t >> 2, lq = (t & 3) * 16;
  u16x8 o0, o1;
#pragma unroll
  for (int j = 0; j < 8; ++j) { o0[j] = tile[lq + j][dd]; o1[j] = tile[lq + 8 + j][dd]; }
  u16* dst = Vt + ((size_t)bh << 18) + ((size_t)(d0 + dd) << 11) + l0 + lq;
  *(u16x8*)dst = o0;
  *(u16x8*)(dst + 8) = o1;
}

// ---------------- flash attention v3: swapped QK^T, in-register P ----------------
__global__ __launch_bounds__(512, 4) void attn_k(const u16* __restrict__ Q,
                                                 const u16* __restrict__ K,
                                                 const u16* __restrict__ V,
                                                 u16* __restrict__ O) {
  __shared__ u16 sK[2][64 * 128];
  __shared__ u16 sV[2][128 * 64];
  const int tid = threadIdx.x;
  const int lane = tid & 63;
  const int w = tid >> 6;
  const int qr = lane & 15;
  const int kg = lane >> 4;
  const int bh = blockIdx.y;
  const size_t bbase = (size_t)(bh >> 4) * (2048 * 2048);
  const int hoff = (bh & 15) * 128;
  const int q0 = blockIdx.x * 128 + w * 16;

  const u16* Qrow = Q + bbase + (size_t)(q0 + qr) * 2048 + hoff;
  const u16* Kh = K + bbase + hoff;
  const u16* Vh = V + ((size_t)bh << 18);

  int kOff[2], vOff[2];
#pragma unroll
  for (int j = 0; j < 2; ++j) {
    int c = j * 512 + tid;
    int rk = c >> 4, sck = c & 15;
    kOff[j] = rk * 2048 + ((sck ^ (rk & 7)) << 3);
    int rv = c >> 3, scv = c & 7;
    vOff[j] = rv * 2048 + ((scv ^ (rv & 7)) << 3);
  }

#define STAGE_KV(bsel, kof)                                                    \
  {                                                                            \
    _Pragma("unroll") for (int j = 0; j < 2; ++j)                              \
        GLOAD_LDS16(Kh + (size_t)(kof) * 2048 + kOff[j],                       \
                    sK[bsel] + (j * 512 + tid) * 8);                           \
    _Pragma("unroll") for (int j = 0; j < 2; ++j)                              \
        GLOAD_LDS16(Vh + (kof) + vOff[j], sV[bsel] + (j * 512 + tid) * 8);     \
  }

  s16x8 aq[4];
#pragma unroll
  for (int c = 0; c < 4; ++c) aq[c] = *(const s16x8*)(Qrow + c * 32 + kg * 8);

  f32x4 o[8] = {};
  float mrow = -1e30f;
  float lrow = 0.f;
  float mprev[4] = {-1e30f, -1e30f, -1e30f, -1e30f};
  const int srcLo = qr + 32 * (kg & 1);
  const int srcHi = srcLo + 16;

  STAGE_KV(0, 0);
  int buf = 0;

  for (int k0 = 0; k0 < 2048; k0 += 64) {
    if (k0 + 64 < 2048) {
      STAGE_KV(buf ^ 1, k0 + 64);
      asm volatile("s_waitcnt vmcnt(4)" ::: "memory");
    } else {
      asm volatile("s_waitcnt vmcnt(0)" ::: "memory");
    }
    __builtin_amdgcn_s_barrier();
    const u16* sKb = sK[buf];
    const u16* sVb = sV[buf];

    f32x4 st[4];
#pragma unroll
    for (int kt = 0; kt < 4; ++kt) {
      int rn = kt * 16 + qr;
      f32x4 a = {0.f, 0.f, 0.f, 0.f};
#pragma unroll
      for (int c = 0; c < 4; ++c) {
        int cc = c * 4 + kg;
        s16x8 bk = *(const s16x8*)(sKb + rn * 128 + ((cc ^ (rn & 7)) << 3));
        a = MFMA16(bk, aq[c], a);
      }
      st[kt] = a;
    }

    float pm = fmaxf(fmaxf(fmaxf(st[0][0], st[0][1]), fmaxf(st[0][2], st[0][3])),
                     fmaxf(fmaxf(st[1][0], st[1][1]), fmaxf(st[1][2], st[1][3])));
    pm = fmaxf(pm,
               fmaxf(fmaxf(fmaxf(st[2][0], st[2][1]), fmaxf(st[2][2], st[2][3])),
                     fmaxf(fmaxf(st[3][0], st[3][1]), fmaxf(st[3][2], st[3][3]))));
    pm = fmaxf(pm, __shfl_xor(pm, 16, 64));
    pm = fmaxf(pm, __shfl_xor(pm, 32, 64));

    if (__any(pm > mrow + 8.f)) {
      float mnew = fmaxf(mrow, pm);
      lrow *= exp2f(mrow - mnew);
      mrow = mnew;
#pragma unroll
      for (int r = 0; r < 4; ++r) {
        float mnr = __shfl(mrow, kg * 4 + r, 64);
        float cfr = exp2f(mprev[r] - mnr);
        mprev[r] = mnr;
#pragma unroll
        for (int dt = 0; dt < 8; ++dt) o[dt][r] *= cfr;
      }
    }

    unsigned w2[8];
    float lsum = 0.f;
#pragma unroll
    for (int kt = 0; kt < 4; ++kt) {
      float p0 = exp2f(st[kt][0] - mrow), p1 = exp2f(st[kt][1] - mrow);
      float p2 = exp2f(st[kt][2] - mrow), p3 = exp2f(st[kt][3] - mrow);
      lsum += (p0 + p1) + (p2 + p3);
      asm("v_cvt_pk_bf16_f32 %0, %1, %2" : "=v"(w2[kt * 2]) : "v"(p0), "v"(p1));
      asm("v_cvt_pk_bf16_f32 %0, %1, %2" : "=v"(w2[kt * 2 + 1]) : "v"(p2), "v"(p3));
    }
    lrow += lsum;

    unsigned pw[8];
#pragma unroll
    for (int f = 0; f < 2; ++f) {
#pragma unroll
      for (int jj = 0; jj < 4; ++jj) {
        int src = (jj < 2) ? srcLo : srcHi;
        unsigned ra = (unsigned)__shfl((int)w2[4 * f + (jj & 1)], src, 64);
        unsigned rb = (unsigned)__shfl((int)w2[4 * f + 2 + (jj & 1)], src, 64);
        pw[f * 4 + jj] = (kg < 2) ? ra : rb;
      }
    }
    union { u32x4 u; s16x8 s; } ua, ub;
    ua.u = (u32x4){pw[0], pw[1], pw[2], pw[3]};
    ub.u = (u32x4){pw[4], pw[5], pw[6], pw[7]};

#pragma unroll
    for (int dt = 0; dt < 8; ++dt) {
      int n = dt * 16 + qr;
      s16x8 bv0 = *(const s16x8*)(sVb + n * 64 + ((kg ^ (n & 7)) << 3));
      s16x8 bv1 = *(const s16x8*)(sVb + n * 64 + (((4 + kg) ^ (n & 7)) << 3));
      o[dt] = MFMA16(ua.s, bv0, o[dt]);
      o[dt] = MFMA16(ub.s, bv1, o[dt]);
    }
    __builtin_amdgcn_s_barrier();
    buf ^= 1;
  }

  lrow += __shfl_xor(lrow, 16, 64);
  lrow += __shfl_xor(lrow, 32, 64);

  u16* Ob = O + bbase + hoff;
#pragma unroll
  for (int r = 0; r < 4; ++r) {
    float inv = 1.0f / __shfl(lrow, kg * 4 + r, 64);
    u16* orow = Ob + (size_t)(q0 + kg * 4 + r) * 2048;
#pragma unroll
    for (int dt = 0; dt < 8; ++dt) orow[dt * 16 + qr] = f2b(o[dt][r] * inv);
  }
#undef STAGE_KV
}

// ---------------- confidence head: logits = out . Wc; conf = sigmoid ----------------
__global__ __launch_bounds__(256) void conf_k(const float* __restrict__ out,
                                              const float* __restrict__ Wc,
                                              float* __restrict__ conf,
                                              float* __restrict__ logits) {
  int row = blockIdx.x * 4 + (threadIdx.x >> 6);  // 4096 rows
  int lane = threadIdx.x & 63;
  const float* r = out + (size_t)row * 2048;
  float sum = 0.f;
#pragma unroll
  for (int j = 0; j < 8; ++j) {
    int i = (j * 64 + lane) * 4;
    float4 a = *(const float4*)(r + i);
    float4 b = *(const float4*)(Wc + i);
    sum += a.x * b.x + a.y * b.y + a.z * b.z + a.w * b.w;
  }
#pragma unroll
  for (int off = 1; off < 64; off <<= 1) sum += __shfl_xor(sum, off, 64);
  if (lane == 0) {
    logits[row] = sum;
    conf[row] = 1.0f / (1.0f + __expf(-sum));
  }
}

extern "C" void kernel_launch(void* const* d_in, const int* in_sizes, int n_in,
                              void* d_out, int out_size, void* d_ws, size_t ws_size,
                              hipStream_t stream) {
  const float* x = (const float*)d_in[0];
  const float* Wq = (const float*)d_in[1];
  const float* Wk = (const float*)d_in[2];
  const float* Wv = (const float*)d_in[3];
  const float* Wo = (const float*)d_in[4];
  const float* Wc = (const float*)d_in[5];
  float* out = (float*)d_out;

  char* ws = (char*)d_ws;
  u16* xb    = (u16*)(ws + 0);          // 16 MB; attn output reuses it
  u16* Wqkvb = (u16*)(ws + 16777216);   // 24 MB [Wq;Wk;Wv] during QKV GEMM
  u16* Wob   = (u16*)(ws + 16777216);   // 8 MB, overwrites Wq slot after QKV
  u16* Vt    = (u16*)(ws + 25165824);   // 16 MB, overwrites Wk/Wv after QKV
  u16* Qb    = (u16*)(ws + 41943040);   // 16 MB
  u16* Kb    = (u16*)(ws + 58720256);   // 16 MB
  u16* Vrow  = (u16*)(ws + 75497472);   // 16 MB (row-major V from QKV GEMM)
  float2* tbl = (float2*)(ws + 92274688);  // 1 MB

  cvt_f32_bf16<<<8192, 256, 0, stream>>>(x, xb, 2097152);
  cvt_w3<<<12288, 256, 0, stream>>>(Wq, Wk, Wv, Wqkvb);
  rope_table_k<<<512, 256, 0, stream>>>(tbl);

  // fused QKV: M=4096, N=6144; grid 24x32 = 768 blocks = 3 exact rounds
  gemm8h<1><<<dim3(24, 32), 512, 0, stream>>>(xb, Wqkvb, nullptr, Qb, Kb, Vrow);

  // V transpose (QKV retired; Wk/Wv region now free)
  transpose_v<<<dim3(64, 32), 256, 0, stream>>>(Vrow, Vt);

  cvt_f32_bf16<<<4096, 256, 0, stream>>>(Wo, Wob, 1048576);

  // qscale = 128^-0.5 * log2(e): attention computes softmax in exp2 domain
  rope_apply_k<<<4096, 256, 0, stream>>>(Qb, Kb, tbl, 0.1275174093403682f);

  attn_k<<<dim3(16, 32), 512, 0, stream>>>(Qb, Kb, Vt, xb);  // xb now holds attn out

  // output projection: M=4096, N=2048; grid 8x32 = 256 blocks = 1 exact round
  gemm8h<0><<<dim3(8, 32), 512, 0, stream>>>(xb, Wob, out, nullptr, nullptr, nullptr);

  conf_k<<<1024, 256, 0, stream>>>(out, Wc, out + 8388608, out + 8392704);
}